// Round 10
// baseline (242.267 us; speedup 1.0000x reference)
//
#include <hip/hip_runtime.h>
#include <math.h>

#define Bv 2
#define Lv 1024
#define Hv 16
#define Dv 64
#define HIDv 1024

typedef unsigned short u16;
typedef short bf16x8 __attribute__((ext_vector_type(8)));
typedef unsigned short u16x4 __attribute__((ext_vector_type(4)));
typedef float f32x4 __attribute__((ext_vector_type(4)));

// round-half-up bf16 (2 inst; tie-to-even dropped — exact ties are measure-zero)
__device__ __forceinline__ u16 f2b(float f) {
    union { float f; unsigned u; } v; v.f = f;
    return (u16)((v.u + 0x8000u) >> 16);
}
__device__ __forceinline__ float b2f(u16 h) {
    union { unsigned u; float f; } v; v.u = ((unsigned)h) << 16;
    return v.f;
}

// async global->LDS, 16B per lane (wave-uniform base + lane*16 order).
__device__ __forceinline__ void gl2lds16(const u16* g, u16* l) {
    __builtin_amdgcn_global_load_lds(
        (const __attribute__((address_space(1))) unsigned int*)g,
        (__attribute__((address_space(3))) unsigned int*)l,
        16, 0, 0);
}

// tanh-form gelu: x * sigmoid(1.5957691*(x + 0.044715*x^3)); max err ~1e-3.
// ~9 VALU (1 exp, 1 rcp) vs ~16 for the A&S erf form.
__device__ __forceinline__ float gelu_fast(float x) {
    float x2 = x * x;
    float inner = __builtin_fmaf(0.044715f * x2, x, x);
    float e = __expf(-1.5957691216057308f * inner);
    return x / (1.0f + e);
}

// ---------------------------------------------------------------------------
// bf16 MFMA GEMM: C = alpha * A @ B^T.
// B staged via global_load_lds (16B/lane). A staged either the same way
// (AF32=false, bf16 source) or via float4 loads + convert (AF32=true).
// LDS tiles contiguous [rows][32] u16 (64B rows).
// ---------------------------------------------------------------------------
template<int BM, int BN, int WM, int WN, bool CBF16, bool AF32>
__global__ __launch_bounds__(256) void gemm_bt(
    const void* __restrict__ Av, const u16* __restrict__ B, void* __restrict__ Cv,
    int M, int N, int K, float alpha)
{
    constexpr int NW = BN / WN;
    constexpr int MI = WM / 16;
    constexpr int NI = WN / 16;
    __shared__ u16 As[BM * 32];
    __shared__ u16 Bs[BN * 32];

    const int m0 = blockIdx.y * BM;
    const int n0 = blockIdx.x * BN;

    const int tid = threadIdx.x;
    const int lane = tid & 63;
    const int wave = tid >> 6;
    const int wm0 = (wave / NW) * WM;
    const int wn0 = (wave % NW) * WN;
    const int fr = lane & 15;
    const int fq = lane >> 4;

    f32x4 acc[MI][NI];
    #pragma unroll
    for (int i = 0; i < MI; ++i)
        #pragma unroll
        for (int j = 0; j < NI; ++j) acc[i][j] = (f32x4){0.f, 0.f, 0.f, 0.f};

    for (int k0 = 0; k0 < K; k0 += 32) {
        if (AF32) {
            const float* Af = (const float*)Av;
            #pragma unroll
            for (int it = 0; it < BM / 64; ++it) {
                int cid = tid + it * 256;
                int r = cid >> 2, ks = (cid & 3) * 8;
                const float* s = Af + (long long)(m0 + r) * K + k0 + ks;
                float4 v0 = *(const float4*)s;
                float4 v1 = *(const float4*)(s + 4);
                u16 o[8] = {f2b(v0.x), f2b(v0.y), f2b(v0.z), f2b(v0.w),
                            f2b(v1.x), f2b(v1.y), f2b(v1.z), f2b(v1.w)};
                *(bf16x8*)&As[r * 32 + ks] = *(bf16x8*)o;
            }
        } else {
            const u16* Au = (const u16*)Av;
            #pragma unroll
            for (int it = 0; it < BM / 64; ++it) {
                int cid = tid + it * 256;
                int r = cid >> 2, ch = cid & 3;
                gl2lds16(Au + (long long)(m0 + r) * K + k0 + ch * 8, &As[cid * 8]);
            }
        }
        #pragma unroll
        for (int it = 0; it < BN / 64; ++it) {
            int cid = tid + it * 256;
            int r = cid >> 2, ch = cid & 3;
            gl2lds16(B + (long long)(n0 + r) * K + k0 + ch * 8, &Bs[cid * 8]);
        }
        __syncthreads();
        bf16x8 af[MI], bfr[NI];
        #pragma unroll
        for (int i = 0; i < MI; ++i)
            af[i] = *(const bf16x8*)&As[(wm0 + i * 16 + fr) * 32 + fq * 8];
        #pragma unroll
        for (int j = 0; j < NI; ++j)
            bfr[j] = *(const bf16x8*)&Bs[(wn0 + j * 16 + fr) * 32 + fq * 8];
        #pragma unroll
        for (int i = 0; i < MI; ++i)
            #pragma unroll
            for (int j = 0; j < NI; ++j)
                acc[i][j] = __builtin_amdgcn_mfma_f32_16x16x32_bf16(
                    af[i], bfr[j], acc[i][j], 0, 0, 0);
        __syncthreads();
    }

    #pragma unroll
    for (int i = 0; i < MI; ++i)
        #pragma unroll
        for (int j = 0; j < NI; ++j)
            #pragma unroll
            for (int r = 0; r < 4; ++r) {
                int row = m0 + wm0 + i * 16 + fq * 4 + r;
                int col = n0 + wn0 + j * 16 + fr;
                float v = acc[i][j][r] * alpha;
                if (CBF16) ((u16*)Cv)[(long long)row * N + col] = f2b(v);
                else      ((float*)Cv)[(long long)row * N + col] = v;
            }
}

// ---------------------------------------------------------------------------
// QK^T direct-from-global (K=64 in fragments; no LDS, no barriers).
// grid (8, 8, B*H); 128x128 tile, 4 waves of 64x64.
// ---------------------------------------------------------------------------
__global__ __launch_bounds__(256) void qk_direct(
    const u16* __restrict__ Q, const u16* __restrict__ K, u16* __restrict__ S)
{
    const int m0 = blockIdx.y * 128;
    const int n0 = blockIdx.x * 128;
    if (n0 > m0) return;
    const u16* A = Q + (long long)blockIdx.z * 65536;
    const u16* B = K + (long long)blockIdx.z * 65536;
    u16* C = S + (long long)blockIdx.z * 1048576;

    const int lane = threadIdx.x & 63;
    const int wave = threadIdx.x >> 6;
    const int wm0 = (wave >> 1) * 64;
    const int wn0 = (wave & 1) * 64;
    const int fr = lane & 15;
    const int fq = lane >> 4;

    bf16x8 af[4][2], bfr[4][2];
    #pragma unroll
    for (int i = 0; i < 4; ++i)
        #pragma unroll
        for (int p = 0; p < 2; ++p) {
            af[i][p]  = *(const bf16x8*)&A[(m0 + wm0 + i * 16 + fr) * 64 + p * 32 + fq * 8];
            bfr[i][p] = *(const bf16x8*)&B[(n0 + wn0 + i * 16 + fr) * 64 + p * 32 + fq * 8];
        }

    f32x4 acc[4][4];
    #pragma unroll
    for (int i = 0; i < 4; ++i)
        #pragma unroll
        for (int j = 0; j < 4; ++j) acc[i][j] = (f32x4){0.f, 0.f, 0.f, 0.f};

    #pragma unroll
    for (int p = 0; p < 2; ++p)
        #pragma unroll
        for (int i = 0; i < 4; ++i)
            #pragma unroll
            for (int j = 0; j < 4; ++j)
                acc[i][j] = __builtin_amdgcn_mfma_f32_16x16x32_bf16(
                    af[i][p], bfr[j][p], acc[i][j], 0, 0, 0);

    #pragma unroll
    for (int i = 0; i < 4; ++i)
        #pragma unroll
        for (int j = 0; j < 4; ++j)
            #pragma unroll
            for (int r = 0; r < 4; ++r) {
                int row = m0 + wm0 + i * 16 + fq * 4 + r;
                int col = n0 + wn0 + j * 16 + fr;
                C[(long long)row * 1024 + col] = f2b(acc[i][j][r] * 0.125f);
            }
}

// ---------------------------------------------------------------------------
// PV direct-from-global (triangular K, no LDS, no barriers).
// grid (16, B*H); writes bf16 into (B,L,H*D).
// ---------------------------------------------------------------------------
__global__ __launch_bounds__(256) void pv_direct(
    const u16* __restrict__ W, const u16* __restrict__ VT, u16* __restrict__ O)
{
    const int m0 = blockIdx.x * 64;
    const int bh = blockIdx.y;
    const u16* A = W + (long long)bh * 1048576;
    const u16* B = VT + (long long)bh * 65536;
    const int b = bh >> 4, h = bh & 15;

    const int lane = threadIdx.x & 63;
    const int wave = threadIdx.x >> 6;
    const int wm0 = (wave >> 1) * 32;
    const int wn0 = (wave & 1) * 32;
    const int fr = lane & 15;
    const int fq = lane >> 4;

    f32x4 acc[2][2];
    #pragma unroll
    for (int i = 0; i < 2; ++i)
        #pragma unroll
        for (int j = 0; j < 2; ++j) acc[i][j] = (f32x4){0.f, 0.f, 0.f, 0.f};

    const int Kend = m0 + 64;
    for (int k0 = 0; k0 < Kend; k0 += 64) {
        bf16x8 af[2][2], bfr[2][2];
        #pragma unroll
        for (int p = 0; p < 2; ++p) {
            #pragma unroll
            for (int i = 0; i < 2; ++i)
                af[p][i] = *(const bf16x8*)&A[(m0 + wm0 + i * 16 + fr) * 1024 + k0 + p * 32 + fq * 8];
            #pragma unroll
            for (int j = 0; j < 2; ++j)
                bfr[p][j] = *(const bf16x8*)&B[(wn0 + j * 16 + fr) * 1024 + k0 + p * 32 + fq * 8];
        }
        #pragma unroll
        for (int p = 0; p < 2; ++p)
            #pragma unroll
            for (int i = 0; i < 2; ++i)
                #pragma unroll
                for (int j = 0; j < 2; ++j)
                    acc[i][j] = __builtin_amdgcn_mfma_f32_16x16x32_bf16(
                        af[p][i], bfr[p][j], acc[i][j], 0, 0, 0);
    }

    const long long ob = (long long)b * 1048576 + h * 64;
    #pragma unroll
    for (int i = 0; i < 2; ++i)
        #pragma unroll
        for (int j = 0; j < 2; ++j)
            #pragma unroll
            for (int r = 0; r < 4; ++r) {
                int row = m0 + wm0 + i * 16 + fq * 4 + r;
                int col = wn0 + j * 16 + fr;
                O[ob + (long long)row * 1024 + col] = f2b(acc[i][j][r]);
            }
}

// ---------------------------------------------------------------------------
// Fused prep: transpose wqkv (blocks 0..767), transpose wo (768..1023),
// kerple table (1024..1087).
// ---------------------------------------------------------------------------
__global__ __launch_bounds__(256) void prep(
    const float* __restrict__ w_qkv, u16* __restrict__ wqkvT,
    const float* __restrict__ w_o, u16* __restrict__ woT,
    const float* __restrict__ log_p, const float* __restrict__ log_a,
    u16* __restrict__ ktab)
{
    __shared__ float tile[64][65];
    const int bid = blockIdx.x;
    const int tid = threadIdx.x;

    if (bid >= 1024) {
        int idx = (bid - 1024) * 256 + tid;    // 16384
        int h = idx & 15, dist = idx >> 4;
        float pp = log1pf(__expf(log_p[h]));
        float aa = log1pf(__expf(log_a[h]));
        ktab[idx] = f2b(-pp * log1pf(aa * (float)dist));
        return;
    }
    const float* src; u16* dst; int M, N, bx, by;
    if (bid < 768) { bx = bid % 48; by = bid / 48; src = w_qkv; dst = wqkvT; M = 1024; N = 3072; }
    else           { int t = bid - 768; bx = t % 16; by = t / 16; src = w_o; dst = woT; M = 1024; N = 1024; }
    const int m0 = by * 64, n0 = bx * 64;
    #pragma unroll
    for (int c = 0; c < 4; ++c) {
        int f = tid + c * 256;
        int r = f >> 4, cs = (f & 15) * 4;
        float4 v = *(const float4*)&src[(long long)(m0 + r) * N + n0 + cs];
        tile[r][cs] = v.x; tile[r][cs + 1] = v.y;
        tile[r][cs + 2] = v.z; tile[r][cs + 3] = v.w;
    }
    __syncthreads();
    int nl = tid >> 2, ms = (tid & 3) * 16;
    u16 outv[16];
    #pragma unroll
    for (int c = 0; c < 16; ++c) outv[c] = f2b(tile[ms + c][nl]);
    *(bf16x8*)&dst[(long long)(n0 + nl) * M + m0 + ms]     = *(bf16x8*)&outv[0];
    *(bf16x8*)&dst[(long long)(n0 + nl) * M + m0 + ms + 8] = *(bf16x8*)&outv[8];
}

// ---------------------------------------------------------------------------
// Fused RoPE + split + V-transpose. grid (L/64, B*H), 256 threads.
// ---------------------------------------------------------------------------
__global__ __launch_bounds__(256) void rope_vt(
    const u16* __restrict__ qkv,
    u16* __restrict__ q, u16* __restrict__ k, u16* __restrict__ vT)
{
    __shared__ u16 tile[64][65];
    const int l0 = blockIdx.x * 64;
    const int bh = blockIdx.y;
    const int b = bh >> 4, h = bh & 15;
    const int tid = threadIdx.x;
    const int r = tid >> 2;
    const int cs = (tid & 3) * 16;
    const int l = l0 + r;
    const long long src = ((long long)(b * 1024 + l) * 3) * 1024 + h * 64;
    const long long qkbase = ((long long)bh * 1024 + l) * 64 + cs;

    float cv[16], sv[16];
    #pragma unroll
    for (int e = 0; e < 16; ++e) {
        int d = cs + e;
        float inv_freq = __expf((float)(d & 31) * -0.28782313662425574f);
        __sincosf((float)l * inv_freq, &sv[e], &cv[e]);
    }
    const int csp = cs ^ 32;
    const float sgn = (cs < 32) ? -1.0f : 1.0f;

    #pragma unroll
    for (int w = 0; w < 2; ++w) {
        const long long s0 = src + w * 1024;
        u16 xv[16], xp[16];
        *(bf16x8*)&xv[0] = *(const bf16x8*)&qkv[s0 + cs];
        *(bf16x8*)&xv[8] = *(const bf16x8*)&qkv[s0 + cs + 8];
        *(bf16x8*)&xp[0] = *(const bf16x8*)&qkv[s0 + csp];
        *(bf16x8*)&xp[8] = *(const bf16x8*)&qkv[s0 + csp + 8];
        u16 o[16];
        #pragma unroll
        for (int e = 0; e < 16; ++e)
            o[e] = f2b(b2f(xv[e]) * cv[e] + sgn * b2f(xp[e]) * sv[e]);
        u16* dst = w ? k : q;
        *(bf16x8*)&dst[qkbase]     = *(bf16x8*)&o[0];
        *(bf16x8*)&dst[qkbase + 8] = *(bf16x8*)&o[8];
    }

    *(bf16x8*)&tile[r][cs]     = *(const bf16x8*)&qkv[src + 2048 + cs];
    *(bf16x8*)&tile[r][cs + 8] = *(const bf16x8*)&qkv[src + 2048 + cs + 8];
    __syncthreads();
    int dl = tid >> 2, ls = (tid & 3) * 16;
    u16 outv[16];
    #pragma unroll
    for (int c = 0; c < 16; ++c) outv[c] = tile[ls + c][dl];
    u16* d = vT + (long long)bh * 65536 + dl * 1024 + l0 + ls;
    *(bf16x8*)&d[0] = *(bf16x8*)&outv[0];
    *(bf16x8*)&d[8] = *(bf16x8*)&outv[8];
}

// ---------------------------------------------------------------------------
// FUSED kerple + DAPE MLP (MFMA) + causal softmax, in-place on bf16 scores.
// 512 threads (8 waves) per (b, i); residual folded into layer-2 MFMA via
// identity B-fragment; wave-autonomous softmax.
// ---------------------------------------------------------------------------
#define LSTR 1044

__global__ __launch_bounds__(512) void dape_soft(
    u16* __restrict__ S, const u16* __restrict__ ktab,
    const float* __restrict__ w1, const float* __restrict__ b1,
    const float* __restrict__ w2, const float* __restrict__ b2)
{
    const int i = 1023 - blockIdx.x;
    const int b = blockIdx.y;

    __shared__ u16 logits[16 * LSTR];
    __shared__ u16 comb[512 * 36];
    __shared__ u16 hid[8][16 * 36];

    const int tid = threadIdx.x;
    const int lane = tid & 63;
    const int wave = tid >> 6;
    const int fr = lane & 15;
    const int fq = lane >> 4;

    bf16x8 B1a, B1b, B2f, Bid;
    #pragma unroll
    for (int e = 0; e < 8; ++e) {
        int c = fq * 8 + e;
        B1a[e] = (short)f2b(w1[c * 32 + fr]);
        B1b[e] = (short)f2b(w1[c * 32 + 16 + fr]);
        B2f[e] = (short)f2b(w2[c * 16 + fr]);
        Bid[e] = (short)((c == fr || c == 16 + fr) ? 0x3F80 : 0);
    }
    const float b1a = b1[fr], b1b = b1[16 + fr], b2v = b2[fr];

    const long long sbase = (long long)b * 16 * 1048576 + (long long)i * 1024;
    const int nchunk = (i >> 9) + 1;

    for (int c = 0; c < nchunk; ++c) {
        const int j = c * 512 + tid;
        {
            u16 row[32];
            #pragma unroll
            for (int h = 0; h < 16; ++h)
                row[h] = S[sbase + (long long)h * 1048576 + j];
            const int dist = (i - j > 0) ? (i - j) : 0;
            *(bf16x8*)&row[16] = *(const bf16x8*)&ktab[dist * 16];
            *(bf16x8*)&row[24] = *(const bf16x8*)&ktab[dist * 16 + 8];
            #pragma unroll
            for (int qq = 0; qq < 4; ++qq)
                *(bf16x8*)&comb[tid * 36 + qq * 8] = *(bf16x8*)&row[qq * 8];
        }
        __syncthreads();

        for (int t = wave; t < 32; t += 8) {
            const int jt = c * 512 + t * 16;
            if (jt > i) continue;

            bf16x8 A1 = *(const bf16x8*)&comb[(t * 16 + fr) * 36 + fq * 8];
            f32x4 z = (f32x4){0.f, 0.f, 0.f, 0.f};
            f32x4 ac1a = __builtin_amdgcn_mfma_f32_16x16x32_bf16(A1, B1a, z, 0, 0, 0);
            f32x4 ac1b = __builtin_amdgcn_mfma_f32_16x16x32_bf16(A1, B1b, z, 0, 0, 0);
            f32x4 cres = __builtin_amdgcn_mfma_f32_16x16x32_bf16(
                A1, Bid, (f32x4){b2v, b2v, b2v, b2v}, 0, 0, 0);

            #pragma unroll
            for (int r = 0; r < 4; ++r) {
                float g0 = gelu_fast(ac1a[r] + b1a);
                float g1 = gelu_fast(ac1b[r] + b1b);
                hid[wave][(fq * 4 + r) * 36 + fr]      = f2b(g0);
                hid[wave][(fq * 4 + r) * 36 + 16 + fr] = f2b(g1);
            }
            bf16x8 A2 = *(const bf16x8*)&hid[wave][fr * 36 + fq * 8];
            f32x4 ac2 = __builtin_amdgcn_mfma_f32_16x16x32_bf16(A2, B2f, cres, 0, 0, 0);

            u16 o[4];
            #pragma unroll
            for (int r = 0; r < 4; ++r) o[r] = f2b(ac2[r]);
            *(u16x4*)&logits[fr * LSTR + jt + fq * 4] = *(u16x4*)o;
        }
        __syncthreads();
    }

    const int we = ((i >> 7) + 1) << 7;
    for (int hh = wave; hh < 16; hh += 8) {
        float vals[16];
        float mx = -3.0e38f;
        #pragma unroll
        for (int s = 0; s < 4; ++s) {
            u16x4 r4 = *(const u16x4*)&logits[hh * LSTR + lane * 4 + 256 * s];
            #pragma unroll
            for (int e = 0; e < 4; ++e) {
                int j = lane * 4 + 256 * s + e;
                float v = (j <= i) ? b2f(r4[e]) : -3.0e38f;
                vals[s * 4 + e] = v;
                mx = fmaxf(mx, v);
            }
        }
        #pragma unroll
        for (int off = 1; off < 64; off <<= 1)
            mx = fmaxf(mx, __shfl_xor(mx, off));
        float sm = 0.f;
        #pragma unroll
        for (int e = 0; e < 16; ++e) {
            float ev = (vals[e] > -1.0e37f) ? __expf(vals[e] - mx) : 0.f;
            vals[e] = ev;
            sm += ev;
        }
        #pragma unroll
        for (int off = 1; off < 64; off <<= 1)
            sm += __shfl_xor(sm, off);
        const float inv = 1.0f / sm;
        const long long hb = sbase + (long long)hh * 1048576;
        #pragma unroll
        for (int s = 0; s < 4; ++s) {
            int j0v = lane * 4 + 256 * s;
            if (j0v < we) {
                u16 o[4];
                #pragma unroll
                for (int e = 0; e < 4; ++e) o[e] = f2b(vals[s * 4 + e] * inv);
                *(u16x4*)&S[hb + j0v] = *(u16x4*)o;
            }
        }
    }
}

// ---------------------------------------------------------------------------
extern "C" void kernel_launch(void* const* d_in, const int* in_sizes, int n_in,
                              void* d_out, int out_size, void* d_ws, size_t ws_size,
                              hipStream_t stream)
{
    const float* x     = (const float*)d_in[0];
    const float* w_qkv = (const float*)d_in[1];
    const float* w_o   = (const float*)d_in[2];
    const float* log_p = (const float*)d_in[3];
    const float* log_a = (const float*)d_in[4];
    const float* w1    = (const float*)d_in[5];
    const float* b1    = (const float*)d_in[6];
    const float* w2    = (const float*)d_in[7];
    const float* b2    = (const float*)d_in[8];
    float* out = (float*)d_out;

    char* p = (char*)d_ws;
    u16* qkv_bf  = (u16*)p;    p += 6291456ll * 2;   // (B,L,3,H,D) bf16
    u16* wqkvT   = (u16*)p;    p += 3145728ll * 2;   // (3HD, HID)
    u16* woT     = (u16*)p;    p += 1048576ll * 2;   // (HID, HD)
    u16* q_bf    = (u16*)p;    p += 2097152ll * 2;   // (B,H,L,D)
    u16* k_bf    = (u16*)p;    p += 2097152ll * 2;
    u16* vT      = (u16*)p;    p += 2097152ll * 2;   // (B,H,D,L)
    u16* scores  = (u16*)p;    p += 33554432ll * 2;  // (B,H,L,L) bf16, in-place
    u16* attn_bf = (u16*)p;    p += 2097152ll * 2;   // (B,L,H*D)
    u16* ktab    = (u16*)p;    p += 16384ll * 2;     // kerple[dist][h]

    // 0. fused prep: transpose weights, kerple table
    prep<<<1088, 256, 0, stream>>>(w_qkv, wqkvT, w_o, woT, log_p, log_a, ktab);

    // 1. qkv = x @ w_qkv (fp32 A staged+cast in-kernel; bf16 out)
    gemm_bt<64, 128, 32, 64, true, true><<<dim3(24, 32, 1), 256, 0, stream>>>(
        x, wqkvT, qkv_bf, 2048, 3072, 1024, 1.0f);

    // 2. fused rope + split + v-transpose
    rope_vt<<<dim3(16, 32), 256, 0, stream>>>(qkv_bf, q_bf, k_bf, vT);

    // 3. scores = (q @ k^T)/8, direct-from-global, causal tiles only
    qk_direct<<<dim3(8, 8, 32), 256, 0, stream>>>(q_bf, k_bf, scores);

    // 4. FUSED kerple + DAPE MLP + softmax
    dape_soft<<<dim3(1024, 2), 512, 0, stream>>>(
        scores, ktab, w1, b1, w2, b2);

    // 5. attn_bf = weights @ v, direct-from-global, triangular K
    pv_direct<<<dim3(16, 32), 256, 0, stream>>>(scores, vT, attn_bf);

    // 6. out = attn_fl @ w_o, 64x64 tiles -> 512 blocks
    gemm_bt<64, 64, 32, 32, false, false><<<dim3(16, 32, 1), 256, 0, stream>>>(
        attn_bf, woT, out, 2048, 1024, 1024, 1.0f);
}

// Round 11
// 234.665 us; speedup vs baseline: 1.0324x; 1.0324x over previous
//
#include <hip/hip_runtime.h>
#include <math.h>

#define Bv 2
#define Lv 1024
#define Hv 16
#define Dv 64
#define HIDv 1024

typedef unsigned short u16;
typedef short bf16x8 __attribute__((ext_vector_type(8)));
typedef unsigned short u16x4 __attribute__((ext_vector_type(4)));
typedef float f32x4 __attribute__((ext_vector_type(4)));

// round-half-up bf16 (2 inst; exact .5-ulp ties are measure-zero)
__device__ __forceinline__ u16 f2b(float f) {
    union { float f; unsigned u; } v; v.f = f;
    return (u16)((v.u + 0x8000u) >> 16);
}
__device__ __forceinline__ float b2f(u16 h) {
    union { unsigned u; float f; } v; v.u = ((unsigned)h) << 16;
    return v.f;
}

// async global->LDS, 16B per lane (wave-uniform base + lane*16 order).
__device__ __forceinline__ void gl2lds16(const u16* g, u16* l) {
    __builtin_amdgcn_global_load_lds(
        (const __attribute__((address_space(1))) unsigned int*)g,
        (__attribute__((address_space(3))) unsigned int*)l,
        16, 0, 0);
}

// tanh-form gelu: x * sigmoid(1.5957691*(x + 0.044715*x^3)); max err ~1e-3.
__device__ __forceinline__ float gelu_fast(float x) {
    float x2 = x * x;
    float inner = __builtin_fmaf(0.044715f * x2, x, x);
    float e = __expf(-1.5957691216057308f * inner);
    return x / (1.0f + e);
}

// ---------------------------------------------------------------------------
// bf16 MFMA GEMM with global_load_lds staging: C = alpha * A @ B^T
// LDS tiles contiguous [rows][32] u16 (64B rows), matching lane*16 order.
// ---------------------------------------------------------------------------
template<int BM, int BN, int WM, int WN, bool CBF16>
__global__ __launch_bounds__(256) void gemm_bt(
    const u16* __restrict__ A, const u16* __restrict__ B, void* __restrict__ Cv,
    int M, int N, int K, float alpha)
{
    constexpr int NW = BN / WN;
    constexpr int MI = WM / 16;
    constexpr int NI = WN / 16;
    __shared__ u16 As[BM * 32];
    __shared__ u16 Bs[BN * 32];

    const int m0 = blockIdx.y * BM;
    const int n0 = blockIdx.x * BN;

    const int tid = threadIdx.x;
    const int lane = tid & 63;
    const int wave = tid >> 6;
    const int wm0 = (wave / NW) * WM;
    const int wn0 = (wave % NW) * WN;
    const int fr = lane & 15;
    const int fq = lane >> 4;

    f32x4 acc[MI][NI];
    #pragma unroll
    for (int i = 0; i < MI; ++i)
        #pragma unroll
        for (int j = 0; j < NI; ++j) acc[i][j] = (f32x4){0.f, 0.f, 0.f, 0.f};

    for (int k0 = 0; k0 < K; k0 += 32) {
        #pragma unroll
        for (int it = 0; it < BM / 64; ++it) {
            int cid = tid + it * 256;
            int r = cid >> 2, ch = cid & 3;
            gl2lds16(A + (long long)(m0 + r) * K + k0 + ch * 8, &As[cid * 8]);
        }
        #pragma unroll
        for (int it = 0; it < BN / 64; ++it) {
            int cid = tid + it * 256;
            int r = cid >> 2, ch = cid & 3;
            gl2lds16(B + (long long)(n0 + r) * K + k0 + ch * 8, &Bs[cid * 8]);
        }
        __syncthreads();
        bf16x8 af[MI], bfr[NI];
        #pragma unroll
        for (int i = 0; i < MI; ++i)
            af[i] = *(const bf16x8*)&As[(wm0 + i * 16 + fr) * 32 + fq * 8];
        #pragma unroll
        for (int j = 0; j < NI; ++j)
            bfr[j] = *(const bf16x8*)&Bs[(wn0 + j * 16 + fr) * 32 + fq * 8];
        #pragma unroll
        for (int i = 0; i < MI; ++i)
            #pragma unroll
            for (int j = 0; j < NI; ++j)
                acc[i][j] = __builtin_amdgcn_mfma_f32_16x16x32_bf16(
                    af[i], bfr[j], acc[i][j], 0, 0, 0);
        __syncthreads();
    }

    #pragma unroll
    for (int i = 0; i < MI; ++i)
        #pragma unroll
        for (int j = 0; j < NI; ++j)
            #pragma unroll
            for (int r = 0; r < 4; ++r) {
                int row = m0 + wm0 + i * 16 + fq * 4 + r;
                int col = n0 + wn0 + j * 16 + fr;
                float v = acc[i][j][r] * alpha;
                if (CBF16) ((u16*)Cv)[(long long)row * N + col] = f2b(v);
                else      ((float*)Cv)[(long long)row * N + col] = v;
            }
}

// ---------------------------------------------------------------------------
// QK^T direct-from-global (K=64 in fragments; no LDS, no barriers).
// grid (8, 8, B*H); 128x128 tile, 4 waves of 64x64.
// ---------------------------------------------------------------------------
__global__ __launch_bounds__(256) void qk_direct(
    const u16* __restrict__ Q, const u16* __restrict__ K, u16* __restrict__ S)
{
    const int m0 = blockIdx.y * 128;
    const int n0 = blockIdx.x * 128;
    if (n0 > m0) return;
    const u16* A = Q + (long long)blockIdx.z * 65536;
    const u16* B = K + (long long)blockIdx.z * 65536;
    u16* C = S + (long long)blockIdx.z * 1048576;

    const int lane = threadIdx.x & 63;
    const int wave = threadIdx.x >> 6;
    const int wm0 = (wave >> 1) * 64;
    const int wn0 = (wave & 1) * 64;
    const int fr = lane & 15;
    const int fq = lane >> 4;

    bf16x8 af[4][2], bfr[4][2];
    #pragma unroll
    for (int i = 0; i < 4; ++i)
        #pragma unroll
        for (int p = 0; p < 2; ++p) {
            af[i][p]  = *(const bf16x8*)&A[(m0 + wm0 + i * 16 + fr) * 64 + p * 32 + fq * 8];
            bfr[i][p] = *(const bf16x8*)&B[(n0 + wn0 + i * 16 + fr) * 64 + p * 32 + fq * 8];
        }

    f32x4 acc[4][4];
    #pragma unroll
    for (int i = 0; i < 4; ++i)
        #pragma unroll
        for (int j = 0; j < 4; ++j) acc[i][j] = (f32x4){0.f, 0.f, 0.f, 0.f};

    #pragma unroll
    for (int p = 0; p < 2; ++p)
        #pragma unroll
        for (int i = 0; i < 4; ++i)
            #pragma unroll
            for (int j = 0; j < 4; ++j)
                acc[i][j] = __builtin_amdgcn_mfma_f32_16x16x32_bf16(
                    af[i][p], bfr[j][p], acc[i][j], 0, 0, 0);

    #pragma unroll
    for (int i = 0; i < 4; ++i)
        #pragma unroll
        for (int j = 0; j < 4; ++j)
            #pragma unroll
            for (int r = 0; r < 4; ++r) {
                int row = m0 + wm0 + i * 16 + fq * 4 + r;
                int col = n0 + wn0 + j * 16 + fr;
                C[(long long)row * 1024 + col] = f2b(acc[i][j][r] * 0.125f);
            }
}

// ---------------------------------------------------------------------------
// PV direct-from-global (triangular K, no LDS, no barriers).
// grid (16, B*H); writes bf16 into (B,L,H*D).
// ---------------------------------------------------------------------------
__global__ __launch_bounds__(256) void pv_direct(
    const u16* __restrict__ W, const u16* __restrict__ VT, u16* __restrict__ O)
{
    const int m0 = blockIdx.x * 64;
    const int bh = blockIdx.y;
    const u16* A = W + (long long)bh * 1048576;
    const u16* B = VT + (long long)bh * 65536;
    const int b = bh >> 4, h = bh & 15;

    const int lane = threadIdx.x & 63;
    const int wave = threadIdx.x >> 6;
    const int wm0 = (wave >> 1) * 32;
    const int wn0 = (wave & 1) * 32;
    const int fr = lane & 15;
    const int fq = lane >> 4;

    f32x4 acc[2][2];
    #pragma unroll
    for (int i = 0; i < 2; ++i)
        #pragma unroll
        for (int j = 0; j < 2; ++j) acc[i][j] = (f32x4){0.f, 0.f, 0.f, 0.f};

    const int Kend = m0 + 64;
    for (int k0 = 0; k0 < Kend; k0 += 64) {
        bf16x8 af[2][2], bfr[2][2];
        #pragma unroll
        for (int p = 0; p < 2; ++p) {
            #pragma unroll
            for (int i = 0; i < 2; ++i)
                af[p][i] = *(const bf16x8*)&A[(m0 + wm0 + i * 16 + fr) * 1024 + k0 + p * 32 + fq * 8];
            #pragma unroll
            for (int j = 0; j < 2; ++j)
                bfr[p][j] = *(const bf16x8*)&B[(wn0 + j * 16 + fr) * 1024 + k0 + p * 32 + fq * 8];
        }
        #pragma unroll
        for (int p = 0; p < 2; ++p)
            #pragma unroll
            for (int i = 0; i < 2; ++i)
                #pragma unroll
                for (int j = 0; j < 2; ++j)
                    acc[i][j] = __builtin_amdgcn_mfma_f32_16x16x32_bf16(
                        af[p][i], bfr[p][j], acc[i][j], 0, 0, 0);
    }

    const long long ob = (long long)b * 1048576 + h * 64;
    #pragma unroll
    for (int i = 0; i < 2; ++i)
        #pragma unroll
        for (int j = 0; j < 2; ++j)
            #pragma unroll
            for (int r = 0; r < 4; ++r) {
                int row = m0 + wm0 + i * 16 + fq * 4 + r;
                int col = wn0 + j * 16 + fr;
                O[ob + (long long)row * 1024 + col] = f2b(acc[i][j][r]);
            }
}

// ---------------------------------------------------------------------------
// Fused prep: cast x (blocks 0..8191), transpose wqkv (..8959),
// transpose wo (..9215), kerple table (..9279).
// ---------------------------------------------------------------------------
__global__ __launch_bounds__(256) void prep(
    const float* __restrict__ x, u16* __restrict__ x_bf,
    const float* __restrict__ w_qkv, u16* __restrict__ wqkvT,
    const float* __restrict__ w_o, u16* __restrict__ woT,
    const float* __restrict__ log_p, const float* __restrict__ log_a,
    u16* __restrict__ ktab)
{
    __shared__ float tile[64][65];
    const int bid = blockIdx.x;
    const int tid = threadIdx.x;

    if (bid < 8192) {
        int i = bid * 256 + tid;
        x_bf[i] = f2b(x[i]);
        return;
    }
    if (bid >= 9216) {
        int idx = (bid - 9216) * 256 + tid;    // 16384
        int h = idx & 15, dist = idx >> 4;
        float pp = log1pf(__expf(log_p[h]));
        float aa = log1pf(__expf(log_a[h]));
        ktab[idx] = f2b(-pp * log1pf(aa * (float)dist));
        return;
    }
    const float* src; u16* dst; int M, N, bx, by;
    if (bid < 8960) { int t = bid - 8192; bx = t % 48; by = t / 48; src = w_qkv; dst = wqkvT; M = 1024; N = 3072; }
    else            { int t = bid - 8960; bx = t % 16; by = t / 16; src = w_o;   dst = woT;   M = 1024; N = 1024; }
    const int m0 = by * 64, n0 = bx * 64;
    #pragma unroll
    for (int c = 0; c < 4; ++c) {
        int f = tid + c * 256;
        int r = f >> 4, cs = (f & 15) * 4;
        float4 v = *(const float4*)&src[(long long)(m0 + r) * N + n0 + cs];
        tile[r][cs] = v.x; tile[r][cs + 1] = v.y;
        tile[r][cs + 2] = v.z; tile[r][cs + 3] = v.w;
    }
    __syncthreads();
    int nl = tid >> 2, ms = (tid & 3) * 16;
    u16 outv[16];
    #pragma unroll
    for (int c = 0; c < 16; ++c) outv[c] = f2b(tile[ms + c][nl]);
    *(bf16x8*)&dst[(long long)(n0 + nl) * M + m0 + ms]     = *(bf16x8*)&outv[0];
    *(bf16x8*)&dst[(long long)(n0 + nl) * M + m0 + ms + 8] = *(bf16x8*)&outv[8];
}

// ---------------------------------------------------------------------------
// Fused RoPE + split + V-transpose. grid (L/64, B*H), 256 threads.
// ---------------------------------------------------------------------------
__global__ __launch_bounds__(256) void rope_vt(
    const u16* __restrict__ qkv,
    u16* __restrict__ q, u16* __restrict__ k, u16* __restrict__ vT)
{
    __shared__ u16 tile[64][65];
    const int l0 = blockIdx.x * 64;
    const int bh = blockIdx.y;
    const int b = bh >> 4, h = bh & 15;
    const int tid = threadIdx.x;
    const int r = tid >> 2;
    const int cs = (tid & 3) * 16;
    const int l = l0 + r;
    const long long src = ((long long)(b * 1024 + l) * 3) * 1024 + h * 64;
    const long long qkbase = ((long long)bh * 1024 + l) * 64 + cs;

    float cv[16], sv[16];
    #pragma unroll
    for (int e = 0; e < 16; ++e) {
        int d = cs + e;
        float inv_freq = __expf((float)(d & 31) * -0.28782313662425574f);
        __sincosf((float)l * inv_freq, &sv[e], &cv[e]);
    }
    const int csp = cs ^ 32;
    const float sgn = (cs < 32) ? -1.0f : 1.0f;

    #pragma unroll
    for (int w = 0; w < 2; ++w) {
        const long long s0 = src + w * 1024;
        u16 xv[16], xp[16];
        *(bf16x8*)&xv[0] = *(const bf16x8*)&qkv[s0 + cs];
        *(bf16x8*)&xv[8] = *(const bf16x8*)&qkv[s0 + cs + 8];
        *(bf16x8*)&xp[0] = *(const bf16x8*)&qkv[s0 + csp];
        *(bf16x8*)&xp[8] = *(const bf16x8*)&qkv[s0 + csp + 8];
        u16 o[16];
        #pragma unroll
        for (int e = 0; e < 16; ++e)
            o[e] = f2b(b2f(xv[e]) * cv[e] + sgn * b2f(xp[e]) * sv[e]);
        u16* dst = w ? k : q;
        *(bf16x8*)&dst[qkbase]     = *(bf16x8*)&o[0];
        *(bf16x8*)&dst[qkbase + 8] = *(bf16x8*)&o[8];
    }

    *(bf16x8*)&tile[r][cs]     = *(const bf16x8*)&qkv[src + 2048 + cs];
    *(bf16x8*)&tile[r][cs + 8] = *(const bf16x8*)&qkv[src + 2048 + cs + 8];
    __syncthreads();
    int dl = tid >> 2, ls = (tid & 3) * 16;
    u16 outv[16];
    #pragma unroll
    for (int c = 0; c < 16; ++c) outv[c] = tile[ls + c][dl];
    u16* d = vT + (long long)bh * 65536 + dl * 1024 + l0 + ls;
    *(bf16x8*)&d[0] = *(bf16x8*)&outv[0];
    *(bf16x8*)&d[8] = *(bf16x8*)&outv[8];
}

// ---------------------------------------------------------------------------
// FUSED kerple + DAPE MLP (MFMA) + causal softmax, in-place on bf16 scores.
// 512 threads (8 waves) per (b, i); residual folded into layer-2 MFMA via
// identity B-fragment; wave-autonomous softmax.
// ---------------------------------------------------------------------------
#define LSTR 1044

__global__ __launch_bounds__(512) void dape_soft(
    u16* __restrict__ S, const u16* __restrict__ ktab,
    const float* __restrict__ w1, const float* __restrict__ b1,
    const float* __restrict__ w2, const float* __restrict__ b2)
{
    const int i = 1023 - blockIdx.x;
    const int b = blockIdx.y;

    __shared__ u16 logits[16 * LSTR];
    __shared__ u16 comb[512 * 36];
    __shared__ u16 hid[8][16 * 36];

    const int tid = threadIdx.x;
    const int lane = tid & 63;
    const int wave = tid >> 6;
    const int fr = lane & 15;
    const int fq = lane >> 4;

    bf16x8 B1a, B1b, B2f, Bid;
    #pragma unroll
    for (int e = 0; e < 8; ++e) {
        int c = fq * 8 + e;
        B1a[e] = (short)f2b(w1[c * 32 + fr]);
        B1b[e] = (short)f2b(w1[c * 32 + 16 + fr]);
        B2f[e] = (short)f2b(w2[c * 16 + fr]);
        Bid[e] = (short)((c == fr || c == 16 + fr) ? 0x3F80 : 0);
    }
    const float b1a = b1[fr], b1b = b1[16 + fr], b2v = b2[fr];

    const long long sbase = (long long)b * 16 * 1048576 + (long long)i * 1024;
    const int nchunk = (i >> 9) + 1;

    for (int c = 0; c < nchunk; ++c) {
        const int j = c * 512 + tid;
        {
            u16 row[32];
            #pragma unroll
            for (int h = 0; h < 16; ++h)
                row[h] = S[sbase + (long long)h * 1048576 + j];
            const int dist = (i - j > 0) ? (i - j) : 0;
            *(bf16x8*)&row[16] = *(const bf16x8*)&ktab[dist * 16];
            *(bf16x8*)&row[24] = *(const bf16x8*)&ktab[dist * 16 + 8];
            #pragma unroll
            for (int qq = 0; qq < 4; ++qq)
                *(bf16x8*)&comb[tid * 36 + qq * 8] = *(bf16x8*)&row[qq * 8];
        }
        __syncthreads();

        for (int t = wave; t < 32; t += 8) {
            const int jt = c * 512 + t * 16;
            if (jt > i) continue;

            bf16x8 A1 = *(const bf16x8*)&comb[(t * 16 + fr) * 36 + fq * 8];
            f32x4 z = (f32x4){0.f, 0.f, 0.f, 0.f};
            f32x4 ac1a = __builtin_amdgcn_mfma_f32_16x16x32_bf16(A1, B1a, z, 0, 0, 0);
            f32x4 ac1b = __builtin_amdgcn_mfma_f32_16x16x32_bf16(A1, B1b, z, 0, 0, 0);
            f32x4 cres = __builtin_amdgcn_mfma_f32_16x16x32_bf16(
                A1, Bid, (f32x4){b2v, b2v, b2v, b2v}, 0, 0, 0);

            #pragma unroll
            for (int r = 0; r < 4; ++r) {
                float g0 = gelu_fast(ac1a[r] + b1a);
                float g1 = gelu_fast(ac1b[r] + b1b);
                hid[wave][(fq * 4 + r) * 36 + fr]      = f2b(g0);
                hid[wave][(fq * 4 + r) * 36 + 16 + fr] = f2b(g1);
            }
            bf16x8 A2 = *(const bf16x8*)&hid[wave][fr * 36 + fq * 8];
            f32x4 ac2 = __builtin_amdgcn_mfma_f32_16x16x32_bf16(A2, B2f, cres, 0, 0, 0);

            u16 o[4];
            #pragma unroll
            for (int r = 0; r < 4; ++r) o[r] = f2b(ac2[r]);
            *(u16x4*)&logits[fr * LSTR + jt + fq * 4] = *(u16x4*)o;
        }
        __syncthreads();
    }

    const int we = ((i >> 7) + 1) << 7;
    for (int hh = wave; hh < 16; hh += 8) {
        float vals[16];
        float mx = -3.0e38f;
        #pragma unroll
        for (int s = 0; s < 4; ++s) {
            u16x4 r4 = *(const u16x4*)&logits[hh * LSTR + lane * 4 + 256 * s];
            #pragma unroll
            for (int e = 0; e < 4; ++e) {
                int j = lane * 4 + 256 * s + e;
                float v = (j <= i) ? b2f(r4[e]) : -3.0e38f;
                vals[s * 4 + e] = v;
                mx = fmaxf(mx, v);
            }
        }
        #pragma unroll
        for (int off = 1; off < 64; off <<= 1)
            mx = fmaxf(mx, __shfl_xor(mx, off));
        float sm = 0.f;
        #pragma unroll
        for (int e = 0; e < 16; ++e) {
            float ev = (vals[e] > -1.0e37f) ? __expf(vals[e] - mx) : 0.f;
            vals[e] = ev;
            sm += ev;
        }
        #pragma unroll
        for (int off = 1; off < 64; off <<= 1)
            sm += __shfl_xor(sm, off);
        const float inv = 1.0f / sm;
        const long long hb = sbase + (long long)hh * 1048576;
        #pragma unroll
        for (int s = 0; s < 4; ++s) {
            int j0v = lane * 4 + 256 * s;
            if (j0v < we) {
                u16 o[4];
                #pragma unroll
                for (int e = 0; e < 4; ++e) o[e] = f2b(vals[s * 4 + e] * inv);
                *(u16x4*)&S[hb + j0v] = *(u16x4*)o;
            }
        }
    }
}

// ---------------------------------------------------------------------------
extern "C" void kernel_launch(void* const* d_in, const int* in_sizes, int n_in,
                              void* d_out, int out_size, void* d_ws, size_t ws_size,
                              hipStream_t stream)
{
    const float* x     = (const float*)d_in[0];
    const float* w_qkv = (const float*)d_in[1];
    const float* w_o   = (const float*)d_in[2];
    const float* log_p = (const float*)d_in[3];
    const float* log_a = (const float*)d_in[4];
    const float* w1    = (const float*)d_in[5];
    const float* b1    = (const float*)d_in[6];
    const float* w2    = (const float*)d_in[7];
    const float* b2    = (const float*)d_in[8];
    float* out = (float*)d_out;

    char* p = (char*)d_ws;
    u16* qkv_bf  = (u16*)p;    p += 6291456ll * 2;   // (B,L,3,H,D) bf16
    u16* x_bf    = (u16*)p;    p += 2097152ll * 2;
    u16* wqkvT   = (u16*)p;    p += 3145728ll * 2;   // (3HD, HID)
    u16* woT     = (u16*)p;    p += 1048576ll * 2;   // (HID, HD)
    u16* q_bf    = (u16*)p;    p += 2097152ll * 2;   // (B,H,L,D)
    u16* k_bf    = (u16*)p;    p += 2097152ll * 2;
    u16* vT      = (u16*)p;    p += 2097152ll * 2;   // (B,H,D,L)
    u16* scores  = (u16*)p;    p += 33554432ll * 2;  // (B,H,L,L) bf16, in-place
    u16* attn_bf = (u16*)p;    p += 2097152ll * 2;   // (B,L,H*D)
    u16* ktab    = (u16*)p;    p += 16384ll * 2;     // kerple[dist][h]

    // 0. fused prep: cast x, transpose weights, kerple table
    prep<<<9280, 256, 0, stream>>>(x, x_bf, w_qkv, wqkvT, w_o, woT,
                                   log_p, log_a, ktab);

    // 1. qkv = x @ w_qkv (bf16, global_load_lds staging)
    gemm_bt<64, 128, 32, 64, true><<<dim3(24, 32, 1), 256, 0, stream>>>(
        x_bf, wqkvT, qkv_bf, 2048, 3072, 1024, 1.0f);

    // 2. fused rope + split + v-transpose
    rope_vt<<<dim3(16, 32), 256, 0, stream>>>(qkv_bf, q_bf, k_bf, vT);

    // 3. scores = (q @ k^T)/8, direct-from-global, causal tiles only
    qk_direct<<<dim3(8, 8, 32), 256, 0, stream>>>(q_bf, k_bf, scores);

    // 4. FUSED kerple + DAPE MLP + softmax
    dape_soft<<<dim3(1024, 2), 512, 0, stream>>>(
        scores, ktab, w1, b1, w2, b2);

    // 5. attn_bf = weights @ v, direct-from-global, triangular K
    pv_direct<<<dim3(16, 32), 256, 0, stream>>>(scores, vT, attn_bf);

    // 6. out = attn_fl @ w_o, 64x64 tiles -> 512 blocks
    gemm_bt<64, 64, 32, 32, false><<<dim3(16, 32, 1), 256, 0, stream>>>(
        attn_bf, woT, out, 2048, 1024, 1024, 1.0f);
}

// Round 12
// 229.207 us; speedup vs baseline: 1.0570x; 1.0238x over previous
//
#include <hip/hip_runtime.h>
#include <math.h>

#define Bv 2
#define Lv 1024
#define Hv 16
#define Dv 64
#define HIDv 1024

typedef unsigned short u16;
typedef short bf16x8 __attribute__((ext_vector_type(8)));
typedef unsigned short u16x4 __attribute__((ext_vector_type(4)));
typedef float f32x4 __attribute__((ext_vector_type(4)));

// round-half-up bf16 (2 inst; exact .5-ulp ties are measure-zero)
__device__ __forceinline__ u16 f2b(float f) {
    union { float f; unsigned u; } v; v.f = f;
    return (u16)((v.u + 0x8000u) >> 16);
}
__device__ __forceinline__ float b2f(u16 h) {
    union { unsigned u; float f; } v; v.u = ((unsigned)h) << 16;
    return v.f;
}

// async global->LDS, 16B per lane (wave-uniform base + lane*16 order).
__device__ __forceinline__ void gl2lds16(const u16* g, u16* l) {
    __builtin_amdgcn_global_load_lds(
        (const __attribute__((address_space(1))) unsigned int*)g,
        (__attribute__((address_space(3))) unsigned int*)l,
        16, 0, 0);
}

// tanh-form gelu: x * sigmoid(1.5957691*(x + 0.044715*x^3)); max err ~1e-3.
__device__ __forceinline__ float gelu_fast(float x) {
    float x2 = x * x;
    float inner = __builtin_fmaf(0.044715f * x2, x, x);
    float e = __expf(-1.5957691216057308f * inner);
    return x / (1.0f + e);
}

// ---------------------------------------------------------------------------
// bf16 MFMA GEMM with global_load_lds staging: C = alpha * A @ B^T.
// Epilogue stages the C tile in LDS (padded) and writes coalesced 16B/lane
// rows — the raw MFMA C-layout store is 4x 32B segments per instruction.
// ---------------------------------------------------------------------------
template<int BM, int BN, int WM, int WN, bool CBF16>
__global__ __launch_bounds__(256) void gemm_bt(
    const u16* __restrict__ A, const u16* __restrict__ B, void* __restrict__ Cv,
    int M, int N, int K, float alpha)
{
    constexpr int NW = BN / WN;
    constexpr int MI = WM / 16;
    constexpr int NI = WN / 16;
    constexpr int LDB = BN + 8;          // bf16 stage row stride (16B-aligned)
    constexpr int LDF = BN + 4;          // f32  stage row stride (16B-aligned)
    __shared__ u16 As[BM * 32];
    __shared__ u16 Bs[BN * 32];
    __shared__ u16 Ctb[CBF16 ? BM * LDB : 1];
    __shared__ float Ctf[CBF16 ? 1 : BM * LDF];

    const int m0 = blockIdx.y * BM;
    const int n0 = blockIdx.x * BN;

    const int tid = threadIdx.x;
    const int lane = tid & 63;
    const int wave = tid >> 6;
    const int wm0 = (wave / NW) * WM;
    const int wn0 = (wave % NW) * WN;
    const int fr = lane & 15;
    const int fq = lane >> 4;

    f32x4 acc[MI][NI];
    #pragma unroll
    for (int i = 0; i < MI; ++i)
        #pragma unroll
        for (int j = 0; j < NI; ++j) acc[i][j] = (f32x4){0.f, 0.f, 0.f, 0.f};

    for (int k0 = 0; k0 < K; k0 += 32) {
        #pragma unroll
        for (int it = 0; it < BM / 64; ++it) {
            int cid = tid + it * 256;
            int r = cid >> 2, ch = cid & 3;
            gl2lds16(A + (long long)(m0 + r) * K + k0 + ch * 8, &As[cid * 8]);
        }
        #pragma unroll
        for (int it = 0; it < BN / 64; ++it) {
            int cid = tid + it * 256;
            int r = cid >> 2, ch = cid & 3;
            gl2lds16(B + (long long)(n0 + r) * K + k0 + ch * 8, &Bs[cid * 8]);
        }
        __syncthreads();
        bf16x8 af[MI], bfr[NI];
        #pragma unroll
        for (int i = 0; i < MI; ++i)
            af[i] = *(const bf16x8*)&As[(wm0 + i * 16 + fr) * 32 + fq * 8];
        #pragma unroll
        for (int j = 0; j < NI; ++j)
            bfr[j] = *(const bf16x8*)&Bs[(wn0 + j * 16 + fr) * 32 + fq * 8];
        #pragma unroll
        for (int i = 0; i < MI; ++i)
            #pragma unroll
            for (int j = 0; j < NI; ++j)
                acc[i][j] = __builtin_amdgcn_mfma_f32_16x16x32_bf16(
                    af[i], bfr[j], acc[i][j], 0, 0, 0);
        __syncthreads();
    }

    // stage C tile in LDS, then coalesced writeback
    #pragma unroll
    for (int i = 0; i < MI; ++i)
        #pragma unroll
        for (int j = 0; j < NI; ++j)
            #pragma unroll
            for (int r = 0; r < 4; ++r) {
                int row = wm0 + i * 16 + fq * 4 + r;
                int col = wn0 + j * 16 + fr;
                float v = acc[i][j][r] * alpha;
                if (CBF16) Ctb[row * LDB + col] = f2b(v);
                else       Ctf[row * LDF + col] = v;
            }
    __syncthreads();
    if (CBF16) {
        constexpr int CPR = BN / 8;              // 16B chunks per row
        #pragma unroll
        for (int c = 0; c < (BM * BN) / (8 * 256); ++c) {
            int cid = tid + c * 256;
            int row = cid / CPR, kc = cid % CPR;
            *(bf16x8*)((u16*)Cv + (long long)(m0 + row) * N + n0 + kc * 8) =
                *(const bf16x8*)&Ctb[row * LDB + kc * 8];
        }
    } else {
        constexpr int CPR = BN / 4;
        #pragma unroll
        for (int c = 0; c < (BM * BN) / (4 * 256); ++c) {
            int cid = tid + c * 256;
            int row = cid / CPR, kc = cid % CPR;
            *(float4*)((float*)Cv + (long long)(m0 + row) * N + n0 + kc * 4) =
                *(const float4*)&Ctf[row * LDF + kc * 4];
        }
    }
}

// ---------------------------------------------------------------------------
// QK^T direct-from-global (K=64 in fragments), LDS-staged coalesced store.
// grid (8, 8, B*H); 128x128 tile, 4 waves of 64x64.
// ---------------------------------------------------------------------------
__global__ __launch_bounds__(256) void qk_direct(
    const u16* __restrict__ Q, const u16* __restrict__ K, u16* __restrict__ S)
{
    const int m0 = blockIdx.y * 128;
    const int n0 = blockIdx.x * 128;
    if (n0 > m0) return;
    const u16* A = Q + (long long)blockIdx.z * 65536;
    const u16* B = K + (long long)blockIdx.z * 65536;
    u16* C = S + (long long)blockIdx.z * 1048576;

    __shared__ u16 Ct[128 * 136];           // 34.8 KB, padded (16B-aligned rows)

    const int tid = threadIdx.x;
    const int lane = tid & 63;
    const int wave = tid >> 6;
    const int wm0 = (wave >> 1) * 64;
    const int wn0 = (wave & 1) * 64;
    const int fr = lane & 15;
    const int fq = lane >> 4;

    bf16x8 af[4][2], bfr[4][2];
    #pragma unroll
    for (int i = 0; i < 4; ++i)
        #pragma unroll
        for (int p = 0; p < 2; ++p) {
            af[i][p]  = *(const bf16x8*)&A[(m0 + wm0 + i * 16 + fr) * 64 + p * 32 + fq * 8];
            bfr[i][p] = *(const bf16x8*)&B[(n0 + wn0 + i * 16 + fr) * 64 + p * 32 + fq * 8];
        }

    f32x4 acc[4][4];
    #pragma unroll
    for (int i = 0; i < 4; ++i)
        #pragma unroll
        for (int j = 0; j < 4; ++j) acc[i][j] = (f32x4){0.f, 0.f, 0.f, 0.f};

    #pragma unroll
    for (int p = 0; p < 2; ++p)
        #pragma unroll
        for (int i = 0; i < 4; ++i)
            #pragma unroll
            for (int j = 0; j < 4; ++j)
                acc[i][j] = __builtin_amdgcn_mfma_f32_16x16x32_bf16(
                    af[i][p], bfr[j][p], acc[i][j], 0, 0, 0);

    #pragma unroll
    for (int i = 0; i < 4; ++i)
        #pragma unroll
        for (int j = 0; j < 4; ++j)
            #pragma unroll
            for (int r = 0; r < 4; ++r)
                Ct[(wm0 + i * 16 + fq * 4 + r) * 136 + wn0 + j * 16 + fr] =
                    f2b(acc[i][j][r] * 0.125f);
    __syncthreads();
    #pragma unroll
    for (int c = 0; c < 8; ++c) {
        int cid = tid + c * 256;
        int row = cid >> 4, kc = cid & 15;
        *(bf16x8*)&C[(long long)(m0 + row) * 1024 + n0 + kc * 8] =
            *(const bf16x8*)&Ct[row * 136 + kc * 8];
    }
}

// ---------------------------------------------------------------------------
// PV direct-from-global (triangular K), LDS-staged coalesced store.
// grid (16, B*H); writes bf16 into (B,L,H*D).
// ---------------------------------------------------------------------------
__global__ __launch_bounds__(256) void pv_direct(
    const u16* __restrict__ W, const u16* __restrict__ VT, u16* __restrict__ O)
{
    const int m0 = blockIdx.x * 64;
    const int bh = blockIdx.y;
    const u16* A = W + (long long)bh * 1048576;
    const u16* B = VT + (long long)bh * 65536;
    const int b = bh >> 4, h = bh & 15;

    __shared__ u16 Ct[64 * 72];             // 9.2 KB, padded

    const int tid = threadIdx.x;
    const int lane = tid & 63;
    const int wave = tid >> 6;
    const int wm0 = (wave >> 1) * 32;
    const int wn0 = (wave & 1) * 32;
    const int fr = lane & 15;
    const int fq = lane >> 4;

    f32x4 acc[2][2];
    #pragma unroll
    for (int i = 0; i < 2; ++i)
        #pragma unroll
        for (int j = 0; j < 2; ++j) acc[i][j] = (f32x4){0.f, 0.f, 0.f, 0.f};

    const int Kend = m0 + 64;
    for (int k0 = 0; k0 < Kend; k0 += 64) {
        bf16x8 af[2][2], bfr[2][2];
        #pragma unroll
        for (int p = 0; p < 2; ++p) {
            #pragma unroll
            for (int i = 0; i < 2; ++i)
                af[p][i] = *(const bf16x8*)&A[(m0 + wm0 + i * 16 + fr) * 1024 + k0 + p * 32 + fq * 8];
            #pragma unroll
            for (int j = 0; j < 2; ++j)
                bfr[p][j] = *(const bf16x8*)&B[(wn0 + j * 16 + fr) * 1024 + k0 + p * 32 + fq * 8];
        }
        #pragma unroll
        for (int p = 0; p < 2; ++p)
            #pragma unroll
            for (int i = 0; i < 2; ++i)
                #pragma unroll
                for (int j = 0; j < 2; ++j)
                    acc[i][j] = __builtin_amdgcn_mfma_f32_16x16x32_bf16(
                        af[p][i], bfr[p][j], acc[i][j], 0, 0, 0);
    }

    #pragma unroll
    for (int i = 0; i < 2; ++i)
        #pragma unroll
        for (int j = 0; j < 2; ++j)
            #pragma unroll
            for (int r = 0; r < 4; ++r)
                Ct[(wm0 + i * 16 + fq * 4 + r) * 72 + wn0 + j * 16 + fr] =
                    f2b(acc[i][j][r]);
    __syncthreads();
    const long long ob = (long long)b * 1048576 + h * 64;
    #pragma unroll
    for (int c = 0; c < 2; ++c) {
        int cid = tid + c * 256;
        int row = cid >> 3, kc = cid & 7;
        *(bf16x8*)&O[ob + (long long)(m0 + row) * 1024 + kc * 8] =
            *(const bf16x8*)&Ct[row * 72 + kc * 8];
    }
}

// ---------------------------------------------------------------------------
// Fused prep: cast x (blocks 0..8191), transpose wqkv (..8959),
// transpose wo (..9215), kerple table (..9279).
// ---------------------------------------------------------------------------
__global__ __launch_bounds__(256) void prep(
    const float* __restrict__ x, u16* __restrict__ x_bf,
    const float* __restrict__ w_qkv, u16* __restrict__ wqkvT,
    const float* __restrict__ w_o, u16* __restrict__ woT,
    const float* __restrict__ log_p, const float* __restrict__ log_a,
    u16* __restrict__ ktab)
{
    __shared__ float tile[64][65];
    const int bid = blockIdx.x;
    const int tid = threadIdx.x;

    if (bid < 8192) {
        int i = bid * 256 + tid;
        x_bf[i] = f2b(x[i]);
        return;
    }
    if (bid >= 9216) {
        int idx = (bid - 9216) * 256 + tid;    // 16384
        int h = idx & 15, dist = idx >> 4;
        float pp = log1pf(__expf(log_p[h]));
        float aa = log1pf(__expf(log_a[h]));
        ktab[idx] = f2b(-pp * log1pf(aa * (float)dist));
        return;
    }
    const float* src; u16* dst; int M, N, bx, by;
    if (bid < 8960) { int t = bid - 8192; bx = t % 48; by = t / 48; src = w_qkv; dst = wqkvT; M = 1024; N = 3072; }
    else            { int t = bid - 8960; bx = t % 16; by = t / 16; src = w_o;   dst = woT;   M = 1024; N = 1024; }
    const int m0 = by * 64, n0 = bx * 64;
    #pragma unroll
    for (int c = 0; c < 4; ++c) {
        int f = tid + c * 256;
        int r = f >> 4, cs = (f & 15) * 4;
        float4 v = *(const float4*)&src[(long long)(m0 + r) * N + n0 + cs];
        tile[r][cs] = v.x; tile[r][cs + 1] = v.y;
        tile[r][cs + 2] = v.z; tile[r][cs + 3] = v.w;
    }
    __syncthreads();
    int nl = tid >> 2, ms = (tid & 3) * 16;
    u16 outv[16];
    #pragma unroll
    for (int c = 0; c < 16; ++c) outv[c] = f2b(tile[ms + c][nl]);
    *(bf16x8*)&dst[(long long)(n0 + nl) * M + m0 + ms]     = *(bf16x8*)&outv[0];
    *(bf16x8*)&dst[(long long)(n0 + nl) * M + m0 + ms + 8] = *(bf16x8*)&outv[8];
}

// ---------------------------------------------------------------------------
// Fused RoPE + split + V-transpose. grid (L/64, B*H), 256 threads.
// ---------------------------------------------------------------------------
__global__ __launch_bounds__(256) void rope_vt(
    const u16* __restrict__ qkv,
    u16* __restrict__ q, u16* __restrict__ k, u16* __restrict__ vT)
{
    __shared__ u16 tile[64][65];
    const int l0 = blockIdx.x * 64;
    const int bh = blockIdx.y;
    const int b = bh >> 4, h = bh & 15;
    const int tid = threadIdx.x;
    const int r = tid >> 2;
    const int cs = (tid & 3) * 16;
    const int l = l0 + r;
    const long long src = ((long long)(b * 1024 + l) * 3) * 1024 + h * 64;
    const long long qkbase = ((long long)bh * 1024 + l) * 64 + cs;

    float cv[16], sv[16];
    #pragma unroll
    for (int e = 0; e < 16; ++e) {
        int d = cs + e;
        float inv_freq = __expf((float)(d & 31) * -0.28782313662425574f);
        __sincosf((float)l * inv_freq, &sv[e], &cv[e]);
    }
    const int csp = cs ^ 32;
    const float sgn = (cs < 32) ? -1.0f : 1.0f;

    #pragma unroll
    for (int w = 0; w < 2; ++w) {
        const long long s0 = src + w * 1024;
        u16 xv[16], xp[16];
        *(bf16x8*)&xv[0] = *(const bf16x8*)&qkv[s0 + cs];
        *(bf16x8*)&xv[8] = *(const bf16x8*)&qkv[s0 + cs + 8];
        *(bf16x8*)&xp[0] = *(const bf16x8*)&qkv[s0 + csp];
        *(bf16x8*)&xp[8] = *(const bf16x8*)&qkv[s0 + csp + 8];
        u16 o[16];
        #pragma unroll
        for (int e = 0; e < 16; ++e)
            o[e] = f2b(b2f(xv[e]) * cv[e] + sgn * b2f(xp[e]) * sv[e]);
        u16* dst = w ? k : q;
        *(bf16x8*)&dst[qkbase]     = *(bf16x8*)&o[0];
        *(bf16x8*)&dst[qkbase + 8] = *(bf16x8*)&o[8];
    }

    *(bf16x8*)&tile[r][cs]     = *(const bf16x8*)&qkv[src + 2048 + cs];
    *(bf16x8*)&tile[r][cs + 8] = *(const bf16x8*)&qkv[src + 2048 + cs + 8];
    __syncthreads();
    int dl = tid >> 2, ls = (tid & 3) * 16;
    u16 outv[16];
    #pragma unroll
    for (int c = 0; c < 16; ++c) outv[c] = tile[ls + c][dl];
    u16* d = vT + (long long)bh * 65536 + dl * 1024 + l0 + ls;
    *(bf16x8*)&d[0] = *(bf16x8*)&outv[0];
    *(bf16x8*)&d[8] = *(bf16x8*)&outv[8];
}

// ---------------------------------------------------------------------------
// FUSED kerple + DAPE MLP (MFMA) + causal softmax, in-place on bf16 scores.
// 512 threads (8 waves) per (b, i); residual folded into layer-2 MFMA via
// identity B-fragment; wave-autonomous softmax.
// ---------------------------------------------------------------------------
#define LSTR 1044

__global__ __launch_bounds__(512) void dape_soft(
    u16* __restrict__ S, const u16* __restrict__ ktab,
    const float* __restrict__ w1, const float* __restrict__ b1,
    const float* __restrict__ w2, const float* __restrict__ b2)
{
    const int i = 1023 - blockIdx.x;
    const int b = blockIdx.y;

    __shared__ u16 logits[16 * LSTR];
    __shared__ u16 comb[512 * 36];
    __shared__ u16 hid[8][16 * 36];

    const int tid = threadIdx.x;
    const int lane = tid & 63;
    const int wave = tid >> 6;
    const int fr = lane & 15;
    const int fq = lane >> 4;

    bf16x8 B1a, B1b, B2f, Bid;
    #pragma unroll
    for (int e = 0; e < 8; ++e) {
        int c = fq * 8 + e;
        B1a[e] = (short)f2b(w1[c * 32 + fr]);
        B1b[e] = (short)f2b(w1[c * 32 + 16 + fr]);
        B2f[e] = (short)f2b(w2[c * 16 + fr]);
        Bid[e] = (short)((c == fr || c == 16 + fr) ? 0x3F80 : 0);
    }
    const float b1a = b1[fr], b1b = b1[16 + fr], b2v = b2[fr];

    const long long sbase = (long long)b * 16 * 1048576 + (long long)i * 1024;
    const int nchunk = (i >> 9) + 1;

    for (int c = 0; c < nchunk; ++c) {
        const int j = c * 512 + tid;
        {
            u16 row[32];
            #pragma unroll
            for (int h = 0; h < 16; ++h)
                row[h] = S[sbase + (long long)h * 1048576 + j];
            const int dist = (i - j > 0) ? (i - j) : 0;
            *(bf16x8*)&row[16] = *(const bf16x8*)&ktab[dist * 16];
            *(bf16x8*)&row[24] = *(const bf16x8*)&ktab[dist * 16 + 8];
            #pragma unroll
            for (int qq = 0; qq < 4; ++qq)
                *(bf16x8*)&comb[tid * 36 + qq * 8] = *(bf16x8*)&row[qq * 8];
        }
        __syncthreads();

        for (int t = wave; t < 32; t += 8) {
            const int jt = c * 512 + t * 16;
            if (jt > i) continue;

            bf16x8 A1 = *(const bf16x8*)&comb[(t * 16 + fr) * 36 + fq * 8];
            f32x4 z = (f32x4){0.f, 0.f, 0.f, 0.f};
            f32x4 ac1a = __builtin_amdgcn_mfma_f32_16x16x32_bf16(A1, B1a, z, 0, 0, 0);
            f32x4 ac1b = __builtin_amdgcn_mfma_f32_16x16x32_bf16(A1, B1b, z, 0, 0, 0);
            f32x4 cres = __builtin_amdgcn_mfma_f32_16x16x32_bf16(
                A1, Bid, (f32x4){b2v, b2v, b2v, b2v}, 0, 0, 0);

            #pragma unroll
            for (int r = 0; r < 4; ++r) {
                float g0 = gelu_fast(ac1a[r] + b1a);
                float g1 = gelu_fast(ac1b[r] + b1b);
                hid[wave][(fq * 4 + r) * 36 + fr]      = f2b(g0);
                hid[wave][(fq * 4 + r) * 36 + 16 + fr] = f2b(g1);
            }
            bf16x8 A2 = *(const bf16x8*)&hid[wave][fr * 36 + fq * 8];
            f32x4 ac2 = __builtin_amdgcn_mfma_f32_16x16x32_bf16(A2, B2f, cres, 0, 0, 0);

            u16 o[4];
            #pragma unroll
            for (int r = 0; r < 4; ++r) o[r] = f2b(ac2[r]);
            *(u16x4*)&logits[fr * LSTR + jt + fq * 4] = *(u16x4*)o;
        }
        __syncthreads();
    }

    const int we = ((i >> 7) + 1) << 7;
    for (int hh = wave; hh < 16; hh += 8) {
        float vals[16];
        float mx = -3.0e38f;
        #pragma unroll
        for (int s = 0; s < 4; ++s) {
            u16x4 r4 = *(const u16x4*)&logits[hh * LSTR + lane * 4 + 256 * s];
            #pragma unroll
            for (int e = 0; e < 4; ++e) {
                int j = lane * 4 + 256 * s + e;
                float v = (j <= i) ? b2f(r4[e]) : -3.0e38f;
                vals[s * 4 + e] = v;
                mx = fmaxf(mx, v);
            }
        }
        #pragma unroll
        for (int off = 1; off < 64; off <<= 1)
            mx = fmaxf(mx, __shfl_xor(mx, off));
        float sm = 0.f;
        #pragma unroll
        for (int e = 0; e < 16; ++e) {
            float ev = (vals[e] > -1.0e37f) ? __expf(vals[e] - mx) : 0.f;
            vals[e] = ev;
            sm += ev;
        }
        #pragma unroll
        for (int off = 1; off < 64; off <<= 1)
            sm += __shfl_xor(sm, off);
        const float inv = 1.0f / sm;
        const long long hb = sbase + (long long)hh * 1048576;
        #pragma unroll
        for (int s = 0; s < 4; ++s) {
            int j0v = lane * 4 + 256 * s;
            if (j0v < we) {
                u16 o[4];
                #pragma unroll
                for (int e = 0; e < 4; ++e) o[e] = f2b(vals[s * 4 + e] * inv);
                *(u16x4*)&S[hb + j0v] = *(u16x4*)o;
            }
        }
    }
}

// ---------------------------------------------------------------------------
extern "C" void kernel_launch(void* const* d_in, const int* in_sizes, int n_in,
                              void* d_out, int out_size, void* d_ws, size_t ws_size,
                              hipStream_t stream)
{
    const float* x     = (const float*)d_in[0];
    const float* w_qkv = (const float*)d_in[1];
    const float* w_o   = (const float*)d_in[2];
    const float* log_p = (const float*)d_in[3];
    const float* log_a = (const float*)d_in[4];
    const float* w1    = (const float*)d_in[5];
    const float* b1    = (const float*)d_in[6];
    const float* w2    = (const float*)d_in[7];
    const float* b2    = (const float*)d_in[8];
    float* out = (float*)d_out;

    char* p = (char*)d_ws;
    u16* qkv_bf  = (u16*)p;    p += 6291456ll * 2;   // (B,L,3,H,D) bf16
    u16* x_bf    = (u16*)p;    p += 2097152ll * 2;
    u16* wqkvT   = (u16*)p;    p += 3145728ll * 2;   // (3HD, HID)
    u16* woT     = (u16*)p;    p += 1048576ll * 2;   // (HID, HD)
    u16* q_bf    = (u16*)p;    p += 2097152ll * 2;   // (B,H,L,D)
    u16* k_bf    = (u16*)p;    p += 2097152ll * 2;
    u16* vT      = (u16*)p;    p += 2097152ll * 2;   // (B,H,D,L)
    u16* scores  = (u16*)p;    p += 33554432ll * 2;  // (B,H,L,L) bf16, in-place
    u16* attn_bf = (u16*)p;    p += 2097152ll * 2;   // (B,L,H*D)
    u16* ktab    = (u16*)p;    p += 16384ll * 2;     // kerple[dist][h]

    // 0. fused prep: cast x, transpose weights, kerple table
    prep<<<9280, 256, 0, stream>>>(x, x_bf, w_qkv, wqkvT, w_o, woT,
                                   log_p, log_a, ktab);

    // 1. qkv = x @ w_qkv (bf16, global_load_lds staging, staged epilogue)
    gemm_bt<64, 128, 32, 64, true><<<dim3(24, 32, 1), 256, 0, stream>>>(
        x_bf, wqkvT, qkv_bf, 2048, 3072, 1024, 1.0f);

    // 2. fused rope + split + v-transpose
    rope_vt<<<dim3(16, 32), 256, 0, stream>>>(qkv_bf, q_bf, k_bf, vT);

    // 3. scores = (q @ k^T)/8, direct-from-global, staged coalesced store
    qk_direct<<<dim3(8, 8, 32), 256, 0, stream>>>(q_bf, k_bf, scores);

    // 4. FUSED kerple + DAPE MLP + softmax
    dape_soft<<<dim3(1024, 2), 512, 0, stream>>>(
        scores, ktab, w1, b1, w2, b2);

    // 5. attn_bf = weights @ v, triangular K, staged coalesced store
    pv_direct<<<dim3(16, 32), 256, 0, stream>>>(scores, vT, attn_bf);

    // 6. out = attn_fl @ w_o, staged epilogue
    gemm_bt<64, 64, 32, 32, false><<<dim3(16, 32, 1), 256, 0, stream>>>(
        attn_bf, woT, out, 2048, 1024, 1024, 1.0f);
}

// Round 13
// 224.142 us; speedup vs baseline: 1.0809x; 1.0226x over previous
//
#include <hip/hip_runtime.h>
#include <math.h>

#define Bv 2
#define Lv 1024
#define Hv 16
#define Dv 64
#define HIDv 1024

typedef unsigned short u16;
typedef short bf16x8 __attribute__((ext_vector_type(8)));
typedef unsigned short u16x4 __attribute__((ext_vector_type(4)));
typedef float f32x4 __attribute__((ext_vector_type(4)));

// round-half-up bf16 (2 inst; exact .5-ulp ties are measure-zero)
__device__ __forceinline__ u16 f2b(float f) {
    union { float f; unsigned u; } v; v.f = f;
    return (u16)((v.u + 0x8000u) >> 16);
}
__device__ __forceinline__ float b2f(u16 h) {
    union { unsigned u; float f; } v; v.u = ((unsigned)h) << 16;
    return v.f;
}

// async global->LDS, 16B per lane (wave-uniform base + lane*16 order).
__device__ __forceinline__ void gl2lds16(const u16* g, u16* l) {
    __builtin_amdgcn_global_load_lds(
        (const __attribute__((address_space(1))) unsigned int*)g,
        (__attribute__((address_space(3))) unsigned int*)l,
        16, 0, 0);
}

// tanh-form gelu: x * sigmoid(1.5957691*(x + 0.044715*x^3)); max err ~1e-3.
__device__ __forceinline__ float gelu_fast(float x) {
    float x2 = x * x;
    float inner = __builtin_fmaf(0.044715f * x2, x, x);
    float e = __expf(-1.5957691216057308f * inner);
    return x / (1.0f + e);
}

// ---------------------------------------------------------------------------
// QKV projection with fused RoPE + split + V-transpose.
// 128x128 tile, 4 waves of 64x64 (16 MFMA/wave/K-step).
// N-tiles 0..7 = q, 8..15 = k (RoPE applied via fp32 tables from staged LDS
// tile; pair d^32 is within the same head's 64 cols), 16..23 = v (stored
// transposed directly from accumulators into vT).
// ---------------------------------------------------------------------------
__global__ __launch_bounds__(256) void qkv_rope(
    const u16* __restrict__ A, const u16* __restrict__ B,
    const float* __restrict__ ctab, const float* __restrict__ stab,
    u16* __restrict__ q, u16* __restrict__ k, u16* __restrict__ vT)
{
    __shared__ u16 As[128 * 32];
    __shared__ u16 Bs[128 * 32];
    __shared__ u16 Ct[128 * 136];

    const int m0 = blockIdx.y * 128;
    const int n0 = blockIdx.x * 128;
    const int K = 1024;

    const int tid = threadIdx.x;
    const int lane = tid & 63;
    const int wave = tid >> 6;
    const int wm0 = (wave >> 1) * 64;
    const int wn0 = (wave & 1) * 64;
    const int fr = lane & 15;
    const int fq = lane >> 4;

    f32x4 acc[4][4];
    #pragma unroll
    for (int i = 0; i < 4; ++i)
        #pragma unroll
        for (int j = 0; j < 4; ++j) acc[i][j] = (f32x4){0.f, 0.f, 0.f, 0.f};

    for (int k0 = 0; k0 < K; k0 += 32) {
        #pragma unroll
        for (int it = 0; it < 2; ++it) {
            int cid = tid + it * 256;
            int r = cid >> 2, ch = cid & 3;
            gl2lds16(A + (long long)(m0 + r) * K + k0 + ch * 8, &As[cid * 8]);
        }
        #pragma unroll
        for (int it = 0; it < 2; ++it) {
            int cid = tid + it * 256;
            int r = cid >> 2, ch = cid & 3;
            gl2lds16(B + (long long)(n0 + r) * K + k0 + ch * 8, &Bs[cid * 8]);
        }
        __syncthreads();
        bf16x8 af[4], bfr[4];
        #pragma unroll
        for (int i = 0; i < 4; ++i)
            af[i] = *(const bf16x8*)&As[(wm0 + i * 16 + fr) * 32 + fq * 8];
        #pragma unroll
        for (int j = 0; j < 4; ++j)
            bfr[j] = *(const bf16x8*)&Bs[(wn0 + j * 16 + fr) * 32 + fq * 8];
        #pragma unroll
        for (int i = 0; i < 4; ++i)
            #pragma unroll
            for (int j = 0; j < 4; ++j)
                acc[i][j] = __builtin_amdgcn_mfma_f32_16x16x32_bf16(
                    af[i], bfr[j], acc[i][j], 0, 0, 0);
        __syncthreads();
    }

    const int b = m0 >> 10;                   // tile never crosses batch

    if (n0 >= 2048) {
        // ---- V: store transposed directly (4 consecutive l per lane) ----
        #pragma unroll
        for (int i = 0; i < 4; ++i)
            #pragma unroll
            for (int j = 0; j < 4; ++j) {
                int vcol = (n0 - 2048) + wn0 + j * 16 + fr;
                int head = vcol >> 6, d = vcol & 63;
                int l = ((m0 + wm0 + i * 16 + fq * 4) & 1023);
                u16 o[4];
                #pragma unroll
                for (int r = 0; r < 4; ++r) o[r] = f2b(acc[i][j][r]);
                *(u16x4*)&vT[((long long)(b * 16 + head) * 64 + d) * 1024 + l] =
                    *(u16x4*)o;
            }
        return;
    }

    // ---- Q/K: stage in LDS, apply RoPE on readback, coalesced store ----
    #pragma unroll
    for (int i = 0; i < 4; ++i)
        #pragma unroll
        for (int j = 0; j < 4; ++j)
            #pragma unroll
            for (int r = 0; r < 4; ++r)
                Ct[(wm0 + i * 16 + fq * 4 + r) * 136 + wn0 + j * 16 + fr] =
                    f2b(acc[i][j][r]);
    __syncthreads();

    u16* dst = (n0 >= 1024) ? k : q;
    const int nh = n0 & 1023;
    #pragma unroll
    for (int c = 0; c < 8; ++c) {
        int cid = tid + c * 256;
        int row = cid >> 4, kc = cid & 15;
        int l = (m0 + row) & 1023;
        int head = (nh >> 6) + (kc >> 3);
        int d0 = (kc & 7) * 8;
        bf16x8 x  = *(const bf16x8*)&Ct[row * 136 + kc * 8];
        bf16x8 xp = *(const bf16x8*)&Ct[row * 136 + (kc ^ 4) * 8];
        float4 c0 = *(const float4*)&ctab[l * 64 + d0];
        float4 c1 = *(const float4*)&ctab[l * 64 + d0 + 4];
        float4 s0 = *(const float4*)&stab[l * 64 + d0];
        float4 s1 = *(const float4*)&stab[l * 64 + d0 + 4];
        float ct[8] = {c0.x, c0.y, c0.z, c0.w, c1.x, c1.y, c1.z, c1.w};
        float st[8] = {s0.x, s0.y, s0.z, s0.w, s1.x, s1.y, s1.z, s1.w};
        u16 o[8];
        #pragma unroll
        for (int e = 0; e < 8; ++e)
            o[e] = f2b(b2f((u16)x[e]) * ct[e] + b2f((u16)xp[e]) * st[e]);
        *(bf16x8*)&dst[((long long)(b * 16 + head) * 1024 + l) * 64 + d0] =
            *(bf16x8*)o;
    }
}

// ---------------------------------------------------------------------------
// bf16 MFMA GEMM with global_load_lds staging: C = alpha * A @ B^T.
// LDS-staged epilogue (used for the out projection).
// ---------------------------------------------------------------------------
template<int BM, int BN, int WM, int WN, bool CBF16>
__global__ __launch_bounds__(256) void gemm_bt(
    const u16* __restrict__ A, const u16* __restrict__ B, void* __restrict__ Cv,
    int M, int N, int K, float alpha)
{
    constexpr int NW = BN / WN;
    constexpr int MI = WM / 16;
    constexpr int NI = WN / 16;
    constexpr int LDB = BN + 8;
    constexpr int LDF = BN + 4;
    __shared__ u16 As[BM * 32];
    __shared__ u16 Bs[BN * 32];
    __shared__ u16 Ctb[CBF16 ? BM * LDB : 1];
    __shared__ float Ctf[CBF16 ? 1 : BM * LDF];

    const int m0 = blockIdx.y * BM;
    const int n0 = blockIdx.x * BN;

    const int tid = threadIdx.x;
    const int lane = tid & 63;
    const int wave = tid >> 6;
    const int wm0 = (wave / NW) * WM;
    const int wn0 = (wave % NW) * WN;
    const int fr = lane & 15;
    const int fq = lane >> 4;

    f32x4 acc[MI][NI];
    #pragma unroll
    for (int i = 0; i < MI; ++i)
        #pragma unroll
        for (int j = 0; j < NI; ++j) acc[i][j] = (f32x4){0.f, 0.f, 0.f, 0.f};

    for (int k0 = 0; k0 < K; k0 += 32) {
        #pragma unroll
        for (int it = 0; it < BM / 64; ++it) {
            int cid = tid + it * 256;
            int r = cid >> 2, ch = cid & 3;
            gl2lds16(A + (long long)(m0 + r) * K + k0 + ch * 8, &As[cid * 8]);
        }
        #pragma unroll
        for (int it = 0; it < BN / 64; ++it) {
            int cid = tid + it * 256;
            int r = cid >> 2, ch = cid & 3;
            gl2lds16(B + (long long)(n0 + r) * K + k0 + ch * 8, &Bs[cid * 8]);
        }
        __syncthreads();
        bf16x8 af[MI], bfr[NI];
        #pragma unroll
        for (int i = 0; i < MI; ++i)
            af[i] = *(const bf16x8*)&As[(wm0 + i * 16 + fr) * 32 + fq * 8];
        #pragma unroll
        for (int j = 0; j < NI; ++j)
            bfr[j] = *(const bf16x8*)&Bs[(wn0 + j * 16 + fr) * 32 + fq * 8];
        #pragma unroll
        for (int i = 0; i < MI; ++i)
            #pragma unroll
            for (int j = 0; j < NI; ++j)
                acc[i][j] = __builtin_amdgcn_mfma_f32_16x16x32_bf16(
                    af[i], bfr[j], acc[i][j], 0, 0, 0);
        __syncthreads();
    }

    #pragma unroll
    for (int i = 0; i < MI; ++i)
        #pragma unroll
        for (int j = 0; j < NI; ++j)
            #pragma unroll
            for (int r = 0; r < 4; ++r) {
                int row = wm0 + i * 16 + fq * 4 + r;
                int col = wn0 + j * 16 + fr;
                float v = acc[i][j][r] * alpha;
                if (CBF16) Ctb[row * LDB + col] = f2b(v);
                else       Ctf[row * LDF + col] = v;
            }
    __syncthreads();
    if (CBF16) {
        constexpr int CPR = BN / 8;
        #pragma unroll
        for (int c = 0; c < (BM * BN) / (8 * 256); ++c) {
            int cid = tid + c * 256;
            int row = cid / CPR, kc = cid % CPR;
            *(bf16x8*)((u16*)Cv + (long long)(m0 + row) * N + n0 + kc * 8) =
                *(const bf16x8*)&Ctb[row * LDB + kc * 8];
        }
    } else {
        constexpr int CPR = BN / 4;
        #pragma unroll
        for (int c = 0; c < (BM * BN) / (4 * 256); ++c) {
            int cid = tid + c * 256;
            int row = cid / CPR, kc = cid % CPR;
            *(float4*)((float*)Cv + (long long)(m0 + row) * N + n0 + kc * 4) =
                *(const float4*)&Ctf[row * LDF + kc * 4];
        }
    }
}

// ---------------------------------------------------------------------------
// QK^T direct-from-global (K=64 in fragments), LDS-staged coalesced store.
// grid (8, 8, B*H); 128x128 tile, 4 waves of 64x64.
// ---------------------------------------------------------------------------
__global__ __launch_bounds__(256) void qk_direct(
    const u16* __restrict__ Q, const u16* __restrict__ K, u16* __restrict__ S)
{
    const int m0 = blockIdx.y * 128;
    const int n0 = blockIdx.x * 128;
    if (n0 > m0) return;
    const u16* A = Q + (long long)blockIdx.z * 65536;
    const u16* B = K + (long long)blockIdx.z * 65536;
    u16* C = S + (long long)blockIdx.z * 1048576;

    __shared__ u16 Ct[128 * 136];

    const int tid = threadIdx.x;
    const int lane = tid & 63;
    const int wave = tid >> 6;
    const int wm0 = (wave >> 1) * 64;
    const int wn0 = (wave & 1) * 64;
    const int fr = lane & 15;
    const int fq = lane >> 4;

    bf16x8 af[4][2], bfr[4][2];
    #pragma unroll
    for (int i = 0; i < 4; ++i)
        #pragma unroll
        for (int p = 0; p < 2; ++p) {
            af[i][p]  = *(const bf16x8*)&A[(m0 + wm0 + i * 16 + fr) * 64 + p * 32 + fq * 8];
            bfr[i][p] = *(const bf16x8*)&B[(n0 + wn0 + i * 16 + fr) * 64 + p * 32 + fq * 8];
        }

    f32x4 acc[4][4];
    #pragma unroll
    for (int i = 0; i < 4; ++i)
        #pragma unroll
        for (int j = 0; j < 4; ++j) acc[i][j] = (f32x4){0.f, 0.f, 0.f, 0.f};

    #pragma unroll
    for (int p = 0; p < 2; ++p)
        #pragma unroll
        for (int i = 0; i < 4; ++i)
            #pragma unroll
            for (int j = 0; j < 4; ++j)
                acc[i][j] = __builtin_amdgcn_mfma_f32_16x16x32_bf16(
                    af[i][p], bfr[j][p], acc[i][j], 0, 0, 0);

    #pragma unroll
    for (int i = 0; i < 4; ++i)
        #pragma unroll
        for (int j = 0; j < 4; ++j)
            #pragma unroll
            for (int r = 0; r < 4; ++r)
                Ct[(wm0 + i * 16 + fq * 4 + r) * 136 + wn0 + j * 16 + fr] =
                    f2b(acc[i][j][r] * 0.125f);
    __syncthreads();
    #pragma unroll
    for (int c = 0; c < 8; ++c) {
        int cid = tid + c * 256;
        int row = cid >> 4, kc = cid & 15;
        *(bf16x8*)&C[(long long)(m0 + row) * 1024 + n0 + kc * 8] =
            *(const bf16x8*)&Ct[row * 136 + kc * 8];
    }
}

// ---------------------------------------------------------------------------
// PV direct-from-global (triangular K), LDS-staged coalesced store.
// grid (16, B*H); writes bf16 into (B,L,H*D).
// ---------------------------------------------------------------------------
__global__ __launch_bounds__(256) void pv_direct(
    const u16* __restrict__ W, const u16* __restrict__ VT, u16* __restrict__ O)
{
    const int m0 = blockIdx.x * 64;
    const int bh = blockIdx.y;
    const u16* A = W + (long long)bh * 1048576;
    const u16* B = VT + (long long)bh * 65536;
    const int b = bh >> 4, h = bh & 15;

    __shared__ u16 Ct[64 * 72];

    const int tid = threadIdx.x;
    const int lane = tid & 63;
    const int wave = tid >> 6;
    const int wm0 = (wave >> 1) * 32;
    const int wn0 = (wave & 1) * 32;
    const int fr = lane & 15;
    const int fq = lane >> 4;

    f32x4 acc[2][2];
    #pragma unroll
    for (int i = 0; i < 2; ++i)
        #pragma unroll
        for (int j = 0; j < 2; ++j) acc[i][j] = (f32x4){0.f, 0.f, 0.f, 0.f};

    const int Kend = m0 + 64;
    for (int k0 = 0; k0 < Kend; k0 += 64) {
        bf16x8 af[2][2], bfr[2][2];
        #pragma unroll
        for (int p = 0; p < 2; ++p) {
            #pragma unroll
            for (int i = 0; i < 2; ++i)
                af[p][i] = *(const bf16x8*)&A[(m0 + wm0 + i * 16 + fr) * 1024 + k0 + p * 32 + fq * 8];
            #pragma unroll
            for (int j = 0; j < 2; ++j)
                bfr[p][j] = *(const bf16x8*)&B[(wn0 + j * 16 + fr) * 1024 + k0 + p * 32 + fq * 8];
        }
        #pragma unroll
        for (int p = 0; p < 2; ++p)
            #pragma unroll
            for (int i = 0; i < 2; ++i)
                #pragma unroll
                for (int j = 0; j < 2; ++j)
                    acc[i][j] = __builtin_amdgcn_mfma_f32_16x16x32_bf16(
                        af[p][i], bfr[p][j], acc[i][j], 0, 0, 0);
    }

    #pragma unroll
    for (int i = 0; i < 2; ++i)
        #pragma unroll
        for (int j = 0; j < 2; ++j)
            #pragma unroll
            for (int r = 0; r < 4; ++r)
                Ct[(wm0 + i * 16 + fq * 4 + r) * 72 + wn0 + j * 16 + fr] =
                    f2b(acc[i][j][r]);
    __syncthreads();
    const long long ob = (long long)b * 1048576 + h * 64;
    #pragma unroll
    for (int c = 0; c < 2; ++c) {
        int cid = tid + c * 256;
        int row = cid >> 3, kc = cid & 7;
        *(bf16x8*)&O[ob + (long long)(m0 + row) * 1024 + kc * 8] =
            *(const bf16x8*)&Ct[row * 72 + kc * 8];
    }
}

// ---------------------------------------------------------------------------
// Fused prep: cast x (blocks 0..8191), transpose wqkv (..8959),
// transpose wo (..9215), kerple table (..9279), rope tables (..9791).
// ---------------------------------------------------------------------------
__global__ __launch_bounds__(256) void prep(
    const float* __restrict__ x, u16* __restrict__ x_bf,
    const float* __restrict__ w_qkv, u16* __restrict__ wqkvT,
    const float* __restrict__ w_o, u16* __restrict__ woT,
    const float* __restrict__ log_p, const float* __restrict__ log_a,
    u16* __restrict__ ktab, float* __restrict__ ctab, float* __restrict__ stab)
{
    __shared__ float tile[64][65];
    const int bid = blockIdx.x;
    const int tid = threadIdx.x;

    if (bid < 8192) {
        int i = bid * 256 + tid;
        x_bf[i] = f2b(x[i]);
        return;
    }
    if (bid >= 9280) {
        int idx = (bid - 9280) * 256 + tid;    // 0..131071: both rope tables
        int e = idx & 65535;
        int l = e >> 6, d = e & 63;
        float inv_freq = __expf((float)(d & 31) * -0.28782313662425574f);
        float arg = (float)l * inv_freq;
        if (idx < 65536) ctab[e] = __cosf(arg);
        else             stab[e] = (d < 32) ? -__sinf(arg) : __sinf(arg);
        return;
    }
    if (bid >= 9216) {
        int idx = (bid - 9216) * 256 + tid;    // 16384
        int h = idx & 15, dist = idx >> 4;
        float pp = log1pf(__expf(log_p[h]));
        float aa = log1pf(__expf(log_a[h]));
        ktab[idx] = f2b(-pp * log1pf(aa * (float)dist));
        return;
    }
    const float* src; u16* dst; int M, N, bx, by;
    if (bid < 8960) { int t = bid - 8192; bx = t % 48; by = t / 48; src = w_qkv; dst = wqkvT; M = 1024; N = 3072; }
    else            { int t = bid - 8960; bx = t % 16; by = t / 16; src = w_o;   dst = woT;   M = 1024; N = 1024; }
    const int m0 = by * 64, n0 = bx * 64;
    #pragma unroll
    for (int c = 0; c < 4; ++c) {
        int f = tid + c * 256;
        int r = f >> 4, cs = (f & 15) * 4;
        float4 v = *(const float4*)&src[(long long)(m0 + r) * N + n0 + cs];
        tile[r][cs] = v.x; tile[r][cs + 1] = v.y;
        tile[r][cs + 2] = v.z; tile[r][cs + 3] = v.w;
    }
    __syncthreads();
    int nl = tid >> 2, ms = (tid & 3) * 16;
    u16 outv[16];
    #pragma unroll
    for (int c = 0; c < 16; ++c) outv[c] = f2b(tile[ms + c][nl]);
    *(bf16x8*)&dst[(long long)(n0 + nl) * M + m0 + ms]     = *(bf16x8*)&outv[0];
    *(bf16x8*)&dst[(long long)(n0 + nl) * M + m0 + ms + 8] = *(bf16x8*)&outv[8];
}

// ---------------------------------------------------------------------------
// FUSED kerple + DAPE MLP (MFMA) + causal softmax, in-place on bf16 scores.
// 512 threads (8 waves) per (b, i); residual folded into layer-2 MFMA via
// identity B-fragment; wave-autonomous softmax.
// ---------------------------------------------------------------------------
#define LSTR 1044

__global__ __launch_bounds__(512) void dape_soft(
    u16* __restrict__ S, const u16* __restrict__ ktab,
    const float* __restrict__ w1, const float* __restrict__ b1,
    const float* __restrict__ w2, const float* __restrict__ b2)
{
    const int i = 1023 - blockIdx.x;
    const int b = blockIdx.y;

    __shared__ u16 logits[16 * LSTR];
    __shared__ u16 comb[512 * 36];
    __shared__ u16 hid[8][16 * 36];

    const int tid = threadIdx.x;
    const int lane = tid & 63;
    const int wave = tid >> 6;
    const int fr = lane & 15;
    const int fq = lane >> 4;

    bf16x8 B1a, B1b, B2f, Bid;
    #pragma unroll
    for (int e = 0; e < 8; ++e) {
        int c = fq * 8 + e;
        B1a[e] = (short)f2b(w1[c * 32 + fr]);
        B1b[e] = (short)f2b(w1[c * 32 + 16 + fr]);
        B2f[e] = (short)f2b(w2[c * 16 + fr]);
        Bid[e] = (short)((c == fr || c == 16 + fr) ? 0x3F80 : 0);
    }
    const float b1a = b1[fr], b1b = b1[16 + fr], b2v = b2[fr];

    const long long sbase = (long long)b * 16 * 1048576 + (long long)i * 1024;
    const int nchunk = (i >> 9) + 1;

    for (int c = 0; c < nchunk; ++c) {
        const int j = c * 512 + tid;
        {
            u16 row[32];
            #pragma unroll
            for (int h = 0; h < 16; ++h)
                row[h] = S[sbase + (long long)h * 1048576 + j];
            const int dist = (i - j > 0) ? (i - j) : 0;
            *(bf16x8*)&row[16] = *(const bf16x8*)&ktab[dist * 16];
            *(bf16x8*)&row[24] = *(const bf16x8*)&ktab[dist * 16 + 8];
            #pragma unroll
            for (int qq = 0; qq < 4; ++qq)
                *(bf16x8*)&comb[tid * 36 + qq * 8] = *(bf16x8*)&row[qq * 8];
        }
        __syncthreads();

        for (int t = wave; t < 32; t += 8) {
            const int jt = c * 512 + t * 16;
            if (jt > i) continue;

            bf16x8 A1 = *(const bf16x8*)&comb[(t * 16 + fr) * 36 + fq * 8];
            f32x4 z = (f32x4){0.f, 0.f, 0.f, 0.f};
            f32x4 ac1a = __builtin_amdgcn_mfma_f32_16x16x32_bf16(A1, B1a, z, 0, 0, 0);
            f32x4 ac1b = __builtin_amdgcn_mfma_f32_16x16x32_bf16(A1, B1b, z, 0, 0, 0);
            f32x4 cres = __builtin_amdgcn_mfma_f32_16x16x32_bf16(
                A1, Bid, (f32x4){b2v, b2v, b2v, b2v}, 0, 0, 0);

            #pragma unroll
            for (int r = 0; r < 4; ++r) {
                float g0 = gelu_fast(ac1a[r] + b1a);
                float g1 = gelu_fast(ac1b[r] + b1b);
                hid[wave][(fq * 4 + r) * 36 + fr]      = f2b(g0);
                hid[wave][(fq * 4 + r) * 36 + 16 + fr] = f2b(g1);
            }
            bf16x8 A2 = *(const bf16x8*)&hid[wave][fr * 36 + fq * 8];
            f32x4 ac2 = __builtin_amdgcn_mfma_f32_16x16x32_bf16(A2, B2f, cres, 0, 0, 0);

            u16 o[4];
            #pragma unroll
            for (int r = 0; r < 4; ++r) o[r] = f2b(ac2[r]);
            *(u16x4*)&logits[fr * LSTR + jt + fq * 4] = *(u16x4*)o;
        }
        __syncthreads();
    }

    const int we = ((i >> 7) + 1) << 7;
    for (int hh = wave; hh < 16; hh += 8) {
        float vals[16];
        float mx = -3.0e38f;
        #pragma unroll
        for (int s = 0; s < 4; ++s) {
            u16x4 r4 = *(const u16x4*)&logits[hh * LSTR + lane * 4 + 256 * s];
            #pragma unroll
            for (int e = 0; e < 4; ++e) {
                int j = lane * 4 + 256 * s + e;
                float v = (j <= i) ? b2f(r4[e]) : -3.0e38f;
                vals[s * 4 + e] = v;
                mx = fmaxf(mx, v);
            }
        }
        #pragma unroll
        for (int off = 1; off < 64; off <<= 1)
            mx = fmaxf(mx, __shfl_xor(mx, off));
        float sm = 0.f;
        #pragma unroll
        for (int e = 0; e < 16; ++e) {
            float ev = (vals[e] > -1.0e37f) ? __expf(vals[e] - mx) : 0.f;
            vals[e] = ev;
            sm += ev;
        }
        #pragma unroll
        for (int off = 1; off < 64; off <<= 1)
            sm += __shfl_xor(sm, off);
        const float inv = 1.0f / sm;
        const long long hb = sbase + (long long)hh * 1048576;
        #pragma unroll
        for (int s = 0; s < 4; ++s) {
            int j0v = lane * 4 + 256 * s;
            if (j0v < we) {
                u16 o[4];
                #pragma unroll
                for (int e = 0; e < 4; ++e) o[e] = f2b(vals[s * 4 + e] * inv);
                *(u16x4*)&S[hb + j0v] = *(u16x4*)o;
            }
        }
    }
}

// ---------------------------------------------------------------------------
extern "C" void kernel_launch(void* const* d_in, const int* in_sizes, int n_in,
                              void* d_out, int out_size, void* d_ws, size_t ws_size,
                              hipStream_t stream)
{
    const float* x     = (const float*)d_in[0];
    const float* w_qkv = (const float*)d_in[1];
    const float* w_o   = (const float*)d_in[2];
    const float* log_p = (const float*)d_in[3];
    const float* log_a = (const float*)d_in[4];
    const float* w1    = (const float*)d_in[5];
    const float* b1    = (const float*)d_in[6];
    const float* w2    = (const float*)d_in[7];
    const float* b2    = (const float*)d_in[8];
    float* out = (float*)d_out;

    char* p = (char*)d_ws;
    u16* x_bf    = (u16*)p;    p += 2097152ll * 2;
    u16* wqkvT   = (u16*)p;    p += 3145728ll * 2;   // (3HD, HID)
    u16* woT     = (u16*)p;    p += 1048576ll * 2;   // (HID, HD)
    u16* q_bf    = (u16*)p;    p += 2097152ll * 2;   // (B,H,L,D)
    u16* k_bf    = (u16*)p;    p += 2097152ll * 2;
    u16* vT      = (u16*)p;    p += 2097152ll * 2;   // (B,H,D,L)
    u16* scores  = (u16*)p;    p += 33554432ll * 2;  // (B,H,L,L) bf16, in-place
    u16* attn_bf = (u16*)p;    p += 2097152ll * 2;   // (B,L,H*D)
    u16* ktab    = (u16*)p;    p += 16384ll * 2;     // kerple[dist][h]
    float* ctab  = (float*)p;  p += 65536ll * 4;     // cos[l][d]
    float* stab  = (float*)p;  p += 65536ll * 4;     // signed sin[l][d]

    // 0. fused prep: cast x, transpose weights, kerple + rope tables
    prep<<<9792, 256, 0, stream>>>(x, x_bf, w_qkv, wqkvT, w_o, woT,
                                   log_p, log_a, ktab, ctab, stab);

    // 1. qkv projection + fused RoPE/split/V-transpose
    qkv_rope<<<dim3(24, 16), 256, 0, stream>>>(
        x_bf, wqkvT, ctab, stab, q_bf, k_bf, vT);

    // 2. scores = (q @ k^T)/8, direct-from-global, staged coalesced store
    qk_direct<<<dim3(8, 8, 32), 256, 0, stream>>>(q_bf, k_bf, scores);

    // 3. FUSED kerple + DAPE MLP + softmax
    dape_soft<<<dim3(1024, 2), 512, 0, stream>>>(
        scores, ktab, w1, b1, w2, b2);

    // 4. attn_bf = weights @ v, triangular K, staged coalesced store
    pv_direct<<<dim3(16, 32), 256, 0, stream>>>(scores, vT, attn_bf);

    // 5. out = attn_fl @ w_o, staged epilogue
    gemm_bt<64, 64, 32, 32, false><<<dim3(16, 32, 1), 256, 0, stream>>>(
        attn_bf, woT, out, 2048, 1024, 1024, 1.0f);
}

// Round 14
// 222.569 us; speedup vs baseline: 1.0885x; 1.0071x over previous
//
#include <hip/hip_runtime.h>
#include <math.h>

#define Bv 2
#define Lv 1024
#define Hv 16
#define Dv 64
#define HIDv 1024

typedef unsigned short u16;
typedef short bf16x8 __attribute__((ext_vector_type(8)));
typedef unsigned short u16x4 __attribute__((ext_vector_type(4)));
typedef float f32x4 __attribute__((ext_vector_type(4)));

// round-half-up bf16 (2 inst; exact .5-ulp ties are measure-zero)
__device__ __forceinline__ u16 f2b(float f) {
    union { float f; unsigned u; } v; v.f = f;
    return (u16)((v.u + 0x8000u) >> 16);
}
__device__ __forceinline__ float b2f(u16 h) {
    union { unsigned u; float f; } v; v.u = ((unsigned)h) << 16;
    return v.f;
}

// async global->LDS, 16B per lane (wave-uniform base + lane*16 order).
__device__ __forceinline__ void gl2lds16(const u16* g, u16* l) {
    __builtin_amdgcn_global_load_lds(
        (const __attribute__((address_space(1))) unsigned int*)g,
        (__attribute__((address_space(3))) unsigned int*)l,
        16, 0, 0);
}

// tanh-form gelu: x * sigmoid(1.5957691*(x + 0.044715*x^3)); max err ~1e-3.
__device__ __forceinline__ float gelu_fast(float x) {
    float x2 = x * x;
    float inner = __builtin_fmaf(0.044715f * x2, x, x);
    float e = __expf(-1.5957691216057308f * inner);
    return x / (1.0f + e);
}

// ---------------------------------------------------------------------------
// QKV projection with fused RoPE + split + V-transpose.
// 128x128 tile, 4 waves of 64x64 (16 MFMA/wave/K-step).
// ---------------------------------------------------------------------------
__global__ __launch_bounds__(256) void qkv_rope(
    const u16* __restrict__ A, const u16* __restrict__ B,
    const float* __restrict__ ctab, const float* __restrict__ stab,
    u16* __restrict__ q, u16* __restrict__ k, u16* __restrict__ vT)
{
    __shared__ u16 As[128 * 32];
    __shared__ u16 Bs[128 * 32];
    __shared__ u16 Ct[128 * 136];

    const int m0 = blockIdx.y * 128;
    const int n0 = blockIdx.x * 128;
    const int K = 1024;

    const int tid = threadIdx.x;
    const int lane = tid & 63;
    const int wave = tid >> 6;
    const int wm0 = (wave >> 1) * 64;
    const int wn0 = (wave & 1) * 64;
    const int fr = lane & 15;
    const int fq = lane >> 4;

    f32x4 acc[4][4];
    #pragma unroll
    for (int i = 0; i < 4; ++i)
        #pragma unroll
        for (int j = 0; j < 4; ++j) acc[i][j] = (f32x4){0.f, 0.f, 0.f, 0.f};

    for (int k0 = 0; k0 < K; k0 += 32) {
        #pragma unroll
        for (int it = 0; it < 2; ++it) {
            int cid = tid + it * 256;
            int r = cid >> 2, ch = cid & 3;
            gl2lds16(A + (long long)(m0 + r) * K + k0 + ch * 8, &As[cid * 8]);
        }
        #pragma unroll
        for (int it = 0; it < 2; ++it) {
            int cid = tid + it * 256;
            int r = cid >> 2, ch = cid & 3;
            gl2lds16(B + (long long)(n0 + r) * K + k0 + ch * 8, &Bs[cid * 8]);
        }
        __syncthreads();
        bf16x8 af[4], bfr[4];
        #pragma unroll
        for (int i = 0; i < 4; ++i)
            af[i] = *(const bf16x8*)&As[(wm0 + i * 16 + fr) * 32 + fq * 8];
        #pragma unroll
        for (int j = 0; j < 4; ++j)
            bfr[j] = *(const bf16x8*)&Bs[(wn0 + j * 16 + fr) * 32 + fq * 8];
        #pragma unroll
        for (int i = 0; i < 4; ++i)
            #pragma unroll
            for (int j = 0; j < 4; ++j)
                acc[i][j] = __builtin_amdgcn_mfma_f32_16x16x32_bf16(
                    af[i], bfr[j], acc[i][j], 0, 0, 0);
        __syncthreads();
    }

    const int b = m0 >> 10;                   // tile never crosses batch

    if (n0 >= 2048) {
        // ---- V: store transposed directly (4 consecutive l per lane) ----
        #pragma unroll
        for (int i = 0; i < 4; ++i)
            #pragma unroll
            for (int j = 0; j < 4; ++j) {
                int vcol = (n0 - 2048) + wn0 + j * 16 + fr;
                int head = vcol >> 6, d = vcol & 63;
                int l = ((m0 + wm0 + i * 16 + fq * 4) & 1023);
                u16 o[4];
                #pragma unroll
                for (int r = 0; r < 4; ++r) o[r] = f2b(acc[i][j][r]);
                *(u16x4*)&vT[((long long)(b * 16 + head) * 64 + d) * 1024 + l] =
                    *(u16x4*)o;
            }
        return;
    }

    // ---- Q/K: stage in LDS, apply RoPE on readback, coalesced store ----
    #pragma unroll
    for (int i = 0; i < 4; ++i)
        #pragma unroll
        for (int j = 0; j < 4; ++j)
            #pragma unroll
            for (int r = 0; r < 4; ++r)
                Ct[(wm0 + i * 16 + fq * 4 + r) * 136 + wn0 + j * 16 + fr] =
                    f2b(acc[i][j][r]);
    __syncthreads();

    u16* dst = (n0 >= 1024) ? k : q;
    const int nh = n0 & 1023;
    #pragma unroll
    for (int c = 0; c < 8; ++c) {
        int cid = tid + c * 256;
        int row = cid >> 4, kc = cid & 15;
        int l = (m0 + row) & 1023;
        int head = (nh >> 6) + (kc >> 3);
        int d0 = (kc & 7) * 8;
        bf16x8 x  = *(const bf16x8*)&Ct[row * 136 + kc * 8];
        bf16x8 xp = *(const bf16x8*)&Ct[row * 136 + (kc ^ 4) * 8];
        float4 c0 = *(const float4*)&ctab[l * 64 + d0];
        float4 c1 = *(const float4*)&ctab[l * 64 + d0 + 4];
        float4 s0 = *(const float4*)&stab[l * 64 + d0];
        float4 s1 = *(const float4*)&stab[l * 64 + d0 + 4];
        float ct[8] = {c0.x, c0.y, c0.z, c0.w, c1.x, c1.y, c1.z, c1.w};
        float st[8] = {s0.x, s0.y, s0.z, s0.w, s1.x, s1.y, s1.z, s1.w};
        u16 o[8];
        #pragma unroll
        for (int e = 0; e < 8; ++e)
            o[e] = f2b(b2f((u16)x[e]) * ct[e] + b2f((u16)xp[e]) * st[e]);
        *(bf16x8*)&dst[((long long)(b * 16 + head) * 1024 + l) * 64 + d0] =
            *(bf16x8*)o;
    }
}

// ---------------------------------------------------------------------------
// bf16 MFMA GEMM with global_load_lds staging: C = alpha * A @ B^T.
// LDS-staged epilogue (used for the out projection).
// ---------------------------------------------------------------------------
template<int BM, int BN, int WM, int WN, bool CBF16>
__global__ __launch_bounds__(256) void gemm_bt(
    const u16* __restrict__ A, const u16* __restrict__ B, void* __restrict__ Cv,
    int M, int N, int K, float alpha)
{
    constexpr int NW = BN / WN;
    constexpr int MI = WM / 16;
    constexpr int NI = WN / 16;
    constexpr int LDB = BN + 8;
    constexpr int LDF = BN + 4;
    __shared__ u16 As[BM * 32];
    __shared__ u16 Bs[BN * 32];
    __shared__ u16 Ctb[CBF16 ? BM * LDB : 1];
    __shared__ float Ctf[CBF16 ? 1 : BM * LDF];

    const int m0 = blockIdx.y * BM;
    const int n0 = blockIdx.x * BN;

    const int tid = threadIdx.x;
    const int lane = tid & 63;
    const int wave = tid >> 6;
    const int wm0 = (wave / NW) * WM;
    const int wn0 = (wave % NW) * WN;
    const int fr = lane & 15;
    const int fq = lane >> 4;

    f32x4 acc[MI][NI];
    #pragma unroll
    for (int i = 0; i < MI; ++i)
        #pragma unroll
        for (int j = 0; j < NI; ++j) acc[i][j] = (f32x4){0.f, 0.f, 0.f, 0.f};

    for (int k0 = 0; k0 < K; k0 += 32) {
        #pragma unroll
        for (int it = 0; it < BM / 64; ++it) {
            int cid = tid + it * 256;
            int r = cid >> 2, ch = cid & 3;
            gl2lds16(A + (long long)(m0 + r) * K + k0 + ch * 8, &As[cid * 8]);
        }
        #pragma unroll
        for (int it = 0; it < BN / 64; ++it) {
            int cid = tid + it * 256;
            int r = cid >> 2, ch = cid & 3;
            gl2lds16(B + (long long)(n0 + r) * K + k0 + ch * 8, &Bs[cid * 8]);
        }
        __syncthreads();
        bf16x8 af[MI], bfr[NI];
        #pragma unroll
        for (int i = 0; i < MI; ++i)
            af[i] = *(const bf16x8*)&As[(wm0 + i * 16 + fr) * 32 + fq * 8];
        #pragma unroll
        for (int j = 0; j < NI; ++j)
            bfr[j] = *(const bf16x8*)&Bs[(wn0 + j * 16 + fr) * 32 + fq * 8];
        #pragma unroll
        for (int i = 0; i < MI; ++i)
            #pragma unroll
            for (int j = 0; j < NI; ++j)
                acc[i][j] = __builtin_amdgcn_mfma_f32_16x16x32_bf16(
                    af[i], bfr[j], acc[i][j], 0, 0, 0);
        __syncthreads();
    }

    #pragma unroll
    for (int i = 0; i < MI; ++i)
        #pragma unroll
        for (int j = 0; j < NI; ++j)
            #pragma unroll
            for (int r = 0; r < 4; ++r) {
                int row = wm0 + i * 16 + fq * 4 + r;
                int col = wn0 + j * 16 + fr;
                float v = acc[i][j][r] * alpha;
                if (CBF16) Ctb[row * LDB + col] = f2b(v);
                else       Ctf[row * LDF + col] = v;
            }
    __syncthreads();
    if (CBF16) {
        constexpr int CPR = BN / 8;
        #pragma unroll
        for (int c = 0; c < (BM * BN) / (8 * 256); ++c) {
            int cid = tid + c * 256;
            int row = cid / CPR, kc = cid % CPR;
            *(bf16x8*)((u16*)Cv + (long long)(m0 + row) * N + n0 + kc * 8) =
                *(const bf16x8*)&Ctb[row * LDB + kc * 8];
        }
    } else {
        constexpr int CPR = BN / 4;
        #pragma unroll
        for (int c = 0; c < (BM * BN) / (4 * 256); ++c) {
            int cid = tid + c * 256;
            int row = cid / CPR, kc = cid % CPR;
            *(float4*)((float*)Cv + (long long)(m0 + row) * N + n0 + kc * 4) =
                *(const float4*)&Ctf[row * LDF + kc * 4];
        }
    }
}

// ---------------------------------------------------------------------------
// QK^T direct-from-global (K=64 in fragments), LDS-staged coalesced store.
// grid (8, 8, B*H); 128x128 tile, 4 waves of 64x64.
// ---------------------------------------------------------------------------
__global__ __launch_bounds__(256) void qk_direct(
    const u16* __restrict__ Q, const u16* __restrict__ K, u16* __restrict__ S)
{
    const int m0 = blockIdx.y * 128;
    const int n0 = blockIdx.x * 128;
    if (n0 > m0) return;
    const u16* A = Q + (long long)blockIdx.z * 65536;
    const u16* B = K + (long long)blockIdx.z * 65536;
    u16* C = S + (long long)blockIdx.z * 1048576;

    __shared__ u16 Ct[128 * 136];

    const int tid = threadIdx.x;
    const int lane = tid & 63;
    const int wave = tid >> 6;
    const int wm0 = (wave >> 1) * 64;
    const int wn0 = (wave & 1) * 64;
    const int fr = lane & 15;
    const int fq = lane >> 4;

    bf16x8 af[4][2], bfr[4][2];
    #pragma unroll
    for (int i = 0; i < 4; ++i)
        #pragma unroll
        for (int p = 0; p < 2; ++p) {
            af[i][p]  = *(const bf16x8*)&A[(m0 + wm0 + i * 16 + fr) * 64 + p * 32 + fq * 8];
            bfr[i][p] = *(const bf16x8*)&B[(n0 + wn0 + i * 16 + fr) * 64 + p * 32 + fq * 8];
        }

    f32x4 acc[4][4];
    #pragma unroll
    for (int i = 0; i < 4; ++i)
        #pragma unroll
        for (int j = 0; j < 4; ++j) acc[i][j] = (f32x4){0.f, 0.f, 0.f, 0.f};

    #pragma unroll
    for (int p = 0; p < 2; ++p)
        #pragma unroll
        for (int i = 0; i < 4; ++i)
            #pragma unroll
            for (int j = 0; j < 4; ++j)
                acc[i][j] = __builtin_amdgcn_mfma_f32_16x16x32_bf16(
                    af[i][p], bfr[j][p], acc[i][j], 0, 0, 0);

    #pragma unroll
    for (int i = 0; i < 4; ++i)
        #pragma unroll
        for (int j = 0; j < 4; ++j)
            #pragma unroll
            for (int r = 0; r < 4; ++r)
                Ct[(wm0 + i * 16 + fq * 4 + r) * 136 + wn0 + j * 16 + fr] =
                    f2b(acc[i][j][r] * 0.125f);
    __syncthreads();
    #pragma unroll
    for (int c = 0; c < 8; ++c) {
        int cid = tid + c * 256;
        int row = cid >> 4, kc = cid & 15;
        *(bf16x8*)&C[(long long)(m0 + row) * 1024 + n0 + kc * 8] =
            *(const bf16x8*)&Ct[row * 136 + kc * 8];
    }
}

// ---------------------------------------------------------------------------
// PV direct-from-global (triangular K), LDS-staged coalesced store.
// grid (16, B*H); writes bf16 into (B,L,H*D).
// ---------------------------------------------------------------------------
__global__ __launch_bounds__(256) void pv_direct(
    const u16* __restrict__ W, const u16* __restrict__ VT, u16* __restrict__ O)
{
    const int m0 = blockIdx.x * 64;
    const int bh = blockIdx.y;
    const u16* A = W + (long long)bh * 1048576;
    const u16* B = VT + (long long)bh * 65536;
    const int b = bh >> 4, h = bh & 15;

    __shared__ u16 Ct[64 * 72];

    const int tid = threadIdx.x;
    const int lane = tid & 63;
    const int wave = tid >> 6;
    const int wm0 = (wave >> 1) * 32;
    const int wn0 = (wave & 1) * 32;
    const int fr = lane & 15;
    const int fq = lane >> 4;

    f32x4 acc[2][2];
    #pragma unroll
    for (int i = 0; i < 2; ++i)
        #pragma unroll
        for (int j = 0; j < 2; ++j) acc[i][j] = (f32x4){0.f, 0.f, 0.f, 0.f};

    const int Kend = m0 + 64;
    for (int k0 = 0; k0 < Kend; k0 += 64) {
        bf16x8 af[2][2], bfr[2][2];
        #pragma unroll
        for (int p = 0; p < 2; ++p) {
            #pragma unroll
            for (int i = 0; i < 2; ++i)
                af[p][i] = *(const bf16x8*)&A[(m0 + wm0 + i * 16 + fr) * 1024 + k0 + p * 32 + fq * 8];
            #pragma unroll
            for (int j = 0; j < 2; ++j)
                bfr[p][j] = *(const bf16x8*)&B[(wn0 + j * 16 + fr) * 1024 + k0 + p * 32 + fq * 8];
        }
        #pragma unroll
        for (int p = 0; p < 2; ++p)
            #pragma unroll
            for (int i = 0; i < 2; ++i)
                #pragma unroll
                for (int j = 0; j < 2; ++j)
                    acc[i][j] = __builtin_amdgcn_mfma_f32_16x16x32_bf16(
                        af[p][i], bfr[p][j], acc[i][j], 0, 0, 0);
    }

    #pragma unroll
    for (int i = 0; i < 2; ++i)
        #pragma unroll
        for (int j = 0; j < 2; ++j)
            #pragma unroll
            for (int r = 0; r < 4; ++r)
                Ct[(wm0 + i * 16 + fq * 4 + r) * 72 + wn0 + j * 16 + fr] =
                    f2b(acc[i][j][r]);
    __syncthreads();
    const long long ob = (long long)b * 1048576 + h * 64;
    #pragma unroll
    for (int c = 0; c < 2; ++c) {
        int cid = tid + c * 256;
        int row = cid >> 3, kc = cid & 7;
        *(bf16x8*)&O[ob + (long long)(m0 + row) * 1024 + kc * 8] =
            *(const bf16x8*)&Ct[row * 72 + kc * 8];
    }
}

// ---------------------------------------------------------------------------
// Fused prep: cast x (blocks 0..8191), transpose wqkv (..8959),
// transpose wo (..9215), kerple table (..9279), rope tables (..9791).
// ---------------------------------------------------------------------------
__global__ __launch_bounds__(256) void prep(
    const float* __restrict__ x, u16* __restrict__ x_bf,
    const float* __restrict__ w_qkv, u16* __restrict__ wqkvT,
    const float* __restrict__ w_o, u16* __restrict__ woT,
    const float* __restrict__ log_p, const float* __restrict__ log_a,
    u16* __restrict__ ktab, float* __restrict__ ctab, float* __restrict__ stab)
{
    __shared__ float tile[64][65];
    const int bid = blockIdx.x;
    const int tid = threadIdx.x;

    if (bid < 8192) {
        int i = bid * 256 + tid;
        x_bf[i] = f2b(x[i]);
        return;
    }
    if (bid >= 9280) {
        int idx = (bid - 9280) * 256 + tid;    // 0..131071: both rope tables
        int e = idx & 65535;
        int l = e >> 6, d = e & 63;
        float inv_freq = __expf((float)(d & 31) * -0.28782313662425574f);
        float arg = (float)l * inv_freq;
        if (idx < 65536) ctab[e] = __cosf(arg);
        else             stab[e] = (d < 32) ? -__sinf(arg) : __sinf(arg);
        return;
    }
    if (bid >= 9216) {
        int idx = (bid - 9216) * 256 + tid;    // 16384
        int h = idx & 15, dist = idx >> 4;
        float pp = log1pf(__expf(log_p[h]));
        float aa = log1pf(__expf(log_a[h]));
        ktab[idx] = f2b(-pp * log1pf(aa * (float)dist));
        return;
    }
    const float* src; u16* dst; int M, N, bx, by;
    if (bid < 8960) { int t = bid - 8192; bx = t % 48; by = t / 48; src = w_qkv; dst = wqkvT; M = 1024; N = 3072; }
    else            { int t = bid - 8960; bx = t % 16; by = t / 16; src = w_o;   dst = woT;   M = 1024; N = 1024; }
    const int m0 = by * 64, n0 = bx * 64;
    #pragma unroll
    for (int c = 0; c < 4; ++c) {
        int f = tid + c * 256;
        int r = f >> 4, cs = (f & 15) * 4;
        float4 v = *(const float4*)&src[(long long)(m0 + r) * N + n0 + cs];
        tile[r][cs] = v.x; tile[r][cs + 1] = v.y;
        tile[r][cs + 2] = v.z; tile[r][cs + 3] = v.w;
    }
    __syncthreads();
    int nl = tid >> 2, ms = (tid & 3) * 16;
    u16 outv[16];
    #pragma unroll
    for (int c = 0; c < 16; ++c) outv[c] = f2b(tile[ms + c][nl]);
    *(bf16x8*)&dst[(long long)(n0 + nl) * M + m0 + ms]     = *(bf16x8*)&outv[0];
    *(bf16x8*)&dst[(long long)(n0 + nl) * M + m0 + ms + 8] = *(bf16x8*)&outv[8];
}

// ---------------------------------------------------------------------------
// FUSED kerple + DAPE MLP (MFMA) + causal softmax, in-place on bf16 scores.
// 512 threads per (b, i). LDS cut to 51.9 KB -> 3 blocks/CU (24 waves):
// 256-position chunks (2 threads stage each position) and the hidden-layer
// transpose buffer OVERLAID on the dead comb tile (A1 already in registers;
// same-wave DS ordering guarantees read-before-write).
// ---------------------------------------------------------------------------
#define LSTR 1044

__global__ __launch_bounds__(512) void dape_soft(
    u16* __restrict__ S, const u16* __restrict__ ktab,
    const float* __restrict__ w1, const float* __restrict__ b1,
    const float* __restrict__ w2, const float* __restrict__ b2)
{
    const int i = 1023 - blockIdx.x;
    const int b = blockIdx.y;

    __shared__ u16 logits[16 * LSTR];        // 33.4 KB
    __shared__ u16 comb[256 * 36];           // 18.4 KB (doubles as hid)

    const int tid = threadIdx.x;
    const int lane = tid & 63;
    const int wave = tid >> 6;
    const int fr = lane & 15;
    const int fq = lane >> 4;

    bf16x8 B1a, B1b, B2f, Bid;
    #pragma unroll
    for (int e = 0; e < 8; ++e) {
        int c = fq * 8 + e;
        B1a[e] = (short)f2b(w1[c * 32 + fr]);
        B1b[e] = (short)f2b(w1[c * 32 + 16 + fr]);
        B2f[e] = (short)f2b(w2[c * 16 + fr]);
        Bid[e] = (short)((c == fr || c == 16 + fr) ? 0x3F80 : 0);
    }
    const float b1a = b1[fr], b1b = b1[16 + fr], b2v = b2[fr];

    const long long sbase = (long long)b * 16 * 1048576 + (long long)i * 1024;
    const int nchunk = (i >> 8) + 1;         // chunks of 256 positions

    for (int c = 0; c < nchunk; ++c) {
        {   // stage: 2 threads per position; each loads 8 head-scores + ktab half
            const int jo = tid & 255;
            const int half = tid >> 8;       // 0 or 1
            const int j = c * 256 + jo;
            u16 row[8];
            #pragma unroll
            for (int h = 0; h < 8; ++h)
                row[h] = S[sbase + (long long)(half * 8 + h) * 1048576 + j];
            const int dist = (i - j > 0) ? (i - j) : 0;
            *(bf16x8*)&comb[jo * 36 + half * 8] = *(bf16x8*)row;
            *(bf16x8*)&comb[jo * 36 + 16 + half * 8] =
                *(const bf16x8*)&ktab[dist * 16 + half * 8];
        }
        __syncthreads();

        for (int t = wave; t < 16; t += 8) {  // 2 tiles per wave
            const int jt = c * 256 + t * 16;
            if (jt > i) continue;

            bf16x8 A1 = *(const bf16x8*)&comb[(t * 16 + fr) * 36 + fq * 8];
            f32x4 z = (f32x4){0.f, 0.f, 0.f, 0.f};
            f32x4 ac1a = __builtin_amdgcn_mfma_f32_16x16x32_bf16(A1, B1a, z, 0, 0, 0);
            f32x4 ac1b = __builtin_amdgcn_mfma_f32_16x16x32_bf16(A1, B1b, z, 0, 0, 0);
            f32x4 cres = __builtin_amdgcn_mfma_f32_16x16x32_bf16(
                A1, Bid, (f32x4){b2v, b2v, b2v, b2v}, 0, 0, 0);

            // hid overlays this wave's (now dead) comb tile region
            u16* hidp = &comb[t * 16 * 36];
            #pragma unroll
            for (int r = 0; r < 4; ++r) {
                float g0 = gelu_fast(ac1a[r] + b1a);
                float g1 = gelu_fast(ac1b[r] + b1b);
                hidp[(fq * 4 + r) * 36 + fr]      = f2b(g0);
                hidp[(fq * 4 + r) * 36 + 16 + fr] = f2b(g1);
            }
            bf16x8 A2 = *(const bf16x8*)&hidp[fr * 36 + fq * 8];
            f32x4 ac2 = __builtin_amdgcn_mfma_f32_16x16x32_bf16(A2, B2f, cres, 0, 0, 0);

            u16 o[4];
            #pragma unroll
            for (int r = 0; r < 4; ++r) o[r] = f2b(ac2[r]);
            *(u16x4*)&logits[fr * LSTR + jt + fq * 4] = *(u16x4*)o;
        }
        __syncthreads();
    }

    // ---- wave-autonomous softmax: wave handles heads {wave, wave+8} ----
    const int we = ((i >> 7) + 1) << 7;
    for (int hh = wave; hh < 16; hh += 8) {
        float vals[16];
        float mx = -3.0e38f;
        #pragma unroll
        for (int s = 0; s < 4; ++s) {
            u16x4 r4 = *(const u16x4*)&logits[hh * LSTR + lane * 4 + 256 * s];
            #pragma unroll
            for (int e = 0; e < 4; ++e) {
                int j = lane * 4 + 256 * s + e;
                float v = (j <= i) ? b2f(r4[e]) : -3.0e38f;
                vals[s * 4 + e] = v;
                mx = fmaxf(mx, v);
            }
        }
        #pragma unroll
        for (int off = 1; off < 64; off <<= 1)
            mx = fmaxf(mx, __shfl_xor(mx, off));
        float sm = 0.f;
        #pragma unroll
        for (int e = 0; e < 16; ++e) {
            float ev = (vals[e] > -1.0e37f) ? __expf(vals[e] - mx) : 0.f;
            vals[e] = ev;
            sm += ev;
        }
        #pragma unroll
        for (int off = 1; off < 64; off <<= 1)
            sm += __shfl_xor(sm, off);
        const float inv = 1.0f / sm;
        const long long hb = sbase + (long long)hh * 1048576;
        #pragma unroll
        for (int s = 0; s < 4; ++s) {
            int j0v = lane * 4 + 256 * s;
            if (j0v < we) {
                u16 o[4];
                #pragma unroll
                for (int e = 0; e < 4; ++e) o[e] = f2b(vals[s * 4 + e] * inv);
                *(u16x4*)&S[hb + j0v] = *(u16x4*)o;
            }
        }
    }
}

// ---------------------------------------------------------------------------
extern "C" void kernel_launch(void* const* d_in, const int* in_sizes, int n_in,
                              void* d_out, int out_size, void* d_ws, size_t ws_size,
                              hipStream_t stream)
{
    const float* x     = (const float*)d_in[0];
    const float* w_qkv = (const float*)d_in[1];
    const float* w_o   = (const float*)d_in[2];
    const float* log_p = (const float*)d_in[3];
    const float* log_a = (const float*)d_in[4];
    const float* w1    = (const float*)d_in[5];
    const float* b1    = (const float*)d_in[6];
    const float* w2    = (const float*)d_in[7];
    const float* b2    = (const float*)d_in[8];
    float* out = (float*)d_out;

    char* p = (char*)d_ws;
    u16* x_bf    = (u16*)p;    p += 2097152ll * 2;
    u16* wqkvT   = (u16*)p;    p += 3145728ll * 2;   // (3HD, HID)
    u16* woT     = (u16*)p;    p += 1048576ll * 2;   // (HID, HD)
    u16* q_bf    = (u16*)p;    p += 2097152ll * 2;   // (B,H,L,D)
    u16* k_bf    = (u16*)p;    p += 2097152ll * 2;
    u16* vT      = (u16*)p;    p += 2097152ll * 2;   // (B,H,D,L)
    u16* scores  = (u16*)p;    p += 33554432ll * 2;  // (B,H,L,L) bf16, in-place
    u16* attn_bf = (u16*)p;    p += 2097152ll * 2;   // (B,L,H*D)
    u16* ktab    = (u16*)p;    p += 16384ll * 2;     // kerple[dist][h]
    float* ctab  = (float*)p;  p += 65536ll * 4;     // cos[l][d]
    float* stab  = (float*)p;  p += 65536ll * 4;     // signed sin[l][d]

    // 0. fused prep: cast x, transpose weights, kerple + rope tables
    prep<<<9792, 256, 0, stream>>>(x, x_bf, w_qkv, wqkvT, w_o, woT,
                                   log_p, log_a, ktab, ctab, stab);

    // 1. qkv projection + fused RoPE/split/V-transpose
    qkv_rope<<<dim3(24, 16), 256, 0, stream>>>(
        x_bf, wqkvT, ctab, stab, q_bf, k_bf, vT);

    // 2. scores = (q @ k^T)/8, direct-from-global, staged coalesced store
    qk_direct<<<dim3(8, 8, 32), 256, 0, stream>>>(q_bf, k_bf, scores);

    // 3. FUSED kerple + DAPE MLP + softmax (3 blocks/CU)
    dape_soft<<<dim3(1024, 2), 512, 0, stream>>>(
        scores, ktab, w1, b1, w2, b2);

    // 4. attn_bf = weights @ v, triangular K, staged coalesced store
    pv_direct<<<dim3(16, 32), 256, 0, stream>>>(scores, vT, attn_bf);

    // 5. out = attn_fl @ w_o, staged epilogue
    gemm_bt<64, 64, 32, 32, false><<<dim3(16, 32, 1), 256, 0, stream>>>(
        attn_bf, woT, out, 2048, 1024, 1024, 1.0f);
}